// Round 6
// baseline (422.896 us; speedup 1.0000x reference)
//
#include <hip/hip_runtime.h>
#include <hip/hip_bf16.h>
#include <cstdint>
#include <cstddef>

typedef __bf16 bf16_t;
typedef __bf16 bf16x8 __attribute__((ext_vector_type(8)));
typedef float f32x4 __attribute__((ext_vector_type(4)));

#define MFMA16(a, b, c) __builtin_amdgcn_mfma_f32_16x16x32_bf16((a), (b), (c), 0, 0, 0)

__device__ __forceinline__ void gload_lds16(const void* g, void* l) {
  __builtin_amdgcn_global_load_lds((__attribute__((address_space(1))) void*)(g),
                                   (__attribute__((address_space(3))) void*)(l),
                                   16, 0, 0);
}

__device__ __forceinline__ uint32_t pkbf(float lo, float hi) {
  union { bf16_t h[2]; uint32_t u; } u2;
  u2.h[0] = (bf16_t)lo; u2.h[1] = (bf16_t)hi;
  return u2.u;
}

// ---------------------------------------------------------------- cvt x fp32->bf16
__global__ __launch_bounds__(256) void cvt_f32_to_bf16(const float* __restrict__ in,
                                                       bf16_t* __restrict__ out) {
  size_t i = ((size_t)blockIdx.x * 256 + threadIdx.x) * 4;
  float4 v = *(const float4*)(in + i);
  bf16_t o[4] = {(bf16_t)v.x, (bf16_t)v.y, (bf16_t)v.z, (bf16_t)v.w};
  *(uint2*)(out + i) = *(uint2*)o;
}

// ---------------------------------------------------------------- weight transpose fp32 (R,C) -> bf16 (C,R)
__global__ __launch_bounds__(256) void transpose_w(const float* __restrict__ in,
                                                   bf16_t* __restrict__ out, int R, int C) {
  __shared__ bf16_t tile[32][33];
  int c0 = blockIdx.x * 32, r0 = blockIdx.y * 32;
  int tx = threadIdx.x, ty = threadIdx.y;
#pragma unroll
  for (int s = 0; s < 4; s++) {
    int r = ty + s * 8;
    tile[r][tx] = (bf16_t)in[(size_t)(r0 + r) * C + c0 + tx];
  }
  __syncthreads();
#pragma unroll
  for (int s = 0; s < 4; s++) {
    int r = ty + s * 8;
    out[(size_t)(c0 + r) * R + r0 + tx] = tile[tx][r];
  }
}

// ---------------------------------------------------------------- v (4096,3072) -> vt (b,h,192,2048)
__global__ __launch_bounds__(256) void transpose_v_kernel(const bf16_t* __restrict__ v,
                                                          bf16_t* __restrict__ vt) {
  __shared__ bf16_t tile[32][33];
  int bh = blockIdx.z;
  int t0 = blockIdx.x * 32, d0 = blockIdx.y * 32;
  int tx = threadIdx.x, ty = threadIdx.y;
  const bf16_t* src = v + (size_t)(bh >> 4) * 2048 * 3072 + (bh & 15) * 192;
#pragma unroll
  for (int s = 0; s < 4; s++) {
    int t = ty + s * 8;
    tile[t][tx] = src[(size_t)(t0 + t) * 3072 + d0 + tx];
  }
  __syncthreads();
  bf16_t* dst = vt + (size_t)bh * 192 * 2048;
#pragma unroll
  for (int s = 0; s < 4; s++) {
    int d = ty + s * 8;
    dst[(size_t)(d0 + d) * 2048 + t0 + tx] = tile[tx][d];
  }
}

// ---------------------------------------------------------------- rope in-place on packed (4096, 16*192) buffer
__global__ __launch_bounds__(256) void rope_inplace(bf16_t* __restrict__ buf) {
  int idx = blockIdx.x * 256 + threadIdx.x;
  int j = idx & 31;
  int h = (idx >> 5) & 15;
  int row = idx >> 9;           // 0..4095
  int t = row & 2047;
  size_t base = (size_t)row * 3072 + h * 192 + 128;
  float inv = expf(-(float)j * 0.28782313662425574f);
  float ang = (float)t * inv;
  float c, s;
  sincosf(ang, &s, &c);
  float x1 = (float)buf[base + j];
  float x2 = (float)buf[base + j + 32];
  buf[base + j]      = (bf16_t)(x1 * c - x2 * s);
  buf[base + j + 32] = (bf16_t)(x1 * s + x2 * c);
}

// ---------------------------------------------------------------- GEMM: C = A(M,lda) [:, :K] * Bt(N,K)^T
template <int MODE>
__global__ __launch_bounds__(256) void gemm_bt(const bf16_t* __restrict__ A, int lda,
                                               const bf16_t* __restrict__ Bt,
                                               void* __restrict__ C0, void* __restrict__ C1,
                                               void* __restrict__ C2, int K, int ldc) {
  __shared__ __align__(16) bf16_t sA[128 * 64];
  __shared__ __align__(16) bf16_t sB[128 * 64];
  const int tid = threadIdx.x;
  const int l = tid & 63, w = tid >> 6;
  const int l15 = l & 15, l4 = l >> 4;
  const int wr = w >> 1, wc = w & 1;
  const int m0 = blockIdx.y * 128, n0 = blockIdx.x * 128;

  f32x4 acc[4][4] = {};

  for (int kt = 0; kt < K; kt += 64) {
#pragma unroll
    for (int r = 0; r < 4; r++) {
      int i = r * 256 + tid;
      int row = i >> 3, cl = i & 7;
      int cg = cl ^ (row & 7);  // pre-swizzled global source, linear LDS dest
      const bf16_t* srcA = A + (size_t)(m0 + row) * lda + kt + cg * 8;
      const bf16_t* srcB = Bt + (size_t)(n0 + row) * K + kt + cg * 8;
      char* dstA = (char*)sA + (size_t)(r * 256 + w * 64) * 16;
      char* dstB = (char*)sB + (size_t)(r * 256 + w * 64) * 16;
      gload_lds16(srcA, dstA);
      gload_lds16(srcB, dstB);
    }
    __syncthreads();
#pragma unroll
    for (int ks = 0; ks < 2; ks++) {
      bf16x8 af[4], bfr[4];
#pragma unroll
      for (int mf = 0; mf < 4; mf++) {
        int row = wr * 64 + mf * 16 + l15;
        int cl = (ks * 4 + l4) ^ (row & 7);
        af[mf] = *(const bf16x8*)(sA + row * 64 + cl * 8);
      }
#pragma unroll
      for (int nf = 0; nf < 4; nf++) {
        int row = wc * 64 + nf * 16 + l15;
        int cl = (ks * 4 + l4) ^ (row & 7);
        bfr[nf] = *(const bf16x8*)(sB + row * 64 + cl * 8);
      }
#pragma unroll
      for (int mf = 0; mf < 4; mf++)
#pragma unroll
        for (int nf = 0; nf < 4; nf++)
          acc[mf][nf] = MFMA16(af[mf], bfr[nf], acc[mf][nf]);
    }
    __syncthreads();
  }

#pragma unroll
  for (int mf = 0; mf < 4; mf++)
#pragma unroll
    for (int nf = 0; nf < 4; nf++)
#pragma unroll
      for (int r = 0; r < 4; r++) {
        int m = m0 + wr * 64 + mf * 16 + l4 * 4 + r;
        int n = n0 + wc * 64 + nf * 16 + l15;
        float v = acc[mf][nf][r];
        if constexpr (MODE == 1) {
          ((float*)C0)[(size_t)m * ldc + n] = v;
        } else if constexpr (MODE == 2) {
          ((bf16_t*)C0)[(size_t)m * 3072 + (n >> 7) * 192 + (n & 127)] = (bf16_t)v;
        } else if constexpr (MODE == 4) {
          if (n < 1280) {
            ((bf16_t*)C0)[(size_t)m * 1280 + n] = (bf16_t)v;
          } else if (n < 2304) {
            int nn = n - 1280;
            ((bf16_t*)C1)[(size_t)m * 3072 + (nn >> 6) * 192 + 128 + (nn & 63)] = (bf16_t)v;
          } else {
            int nn = n - 2304;
            ((bf16_t*)C2)[(size_t)m * 3072 + (nn >> 6) * 192 + 128 + (nn & 63)] = (bf16_t)v;
          }
        } else {  // MODE 5
          if (n < 2048) {
            ((bf16_t*)C0)[(size_t)m * 3072 + (n >> 7) * 192 + (n & 127)] = (bf16_t)v;
          } else {
            ((bf16_t*)C1)[(size_t)m * 3072 + (n - 2048)] = (bf16_t)v;
          }
        }
      }
}

// ---------------------------------------------------------------- flash attention (causal)
// 256 threads / 4 waves per block, one 128-row q-chunk qi per block, nkt = 2qi+2.
// LDS 72KB: K single-buffered, V double-buffered -> 2 blocks/CU. Per tile:
// QK(sK) -> barrier -> issue stage K(kt+1)+V(kt+1) -> softmax+PV(sV[bb]) -> barrier(drain).
// Block remap pairs (qi, 15-qi) on co-resident CU slots; same-bh blocks share an XCD.
__global__ __launch_bounds__(256, 2) void attn_kernel(const bf16_t* __restrict__ q,
                                                      const bf16_t* __restrict__ kbuf,
                                                      const bf16_t* __restrict__ vt,
                                                      bf16_t* __restrict__ ao) {
  __shared__ __align__(16) bf16_t sK[64][192];     // perm-24 swizzle, single
  __shared__ __align__(16) bf16_t sV[2][192][64];  // xor-8 chunk swizzle, dbuf

  const int tid = threadIdx.x, l = tid & 63, w = tid >> 6;
  const int l15 = l & 15, l4 = (l >> 4) & 3;
  const int bid = blockIdx.x;
  const int half = bid >> 8, rr = bid & 255;
  const int bh = rr & 31;
  const int qi = half ? (15 - (rr >> 5)) : (rr >> 5);
  const int b = bh >> 4, h = bh & 15;
  const int rA = qi * 128 + w * 16;   // rows [rA, rA+16)
  const int rB = rA + 64;             // rows [rB, rB+16)
  const int tgA = 2 * qi;             // diag tile of sub-chunk A
  const int nkt = 2 * qi + 2;         // sub-chunk B diag = nkt-1

  const bf16_t* qp = q + (size_t)b * 2048 * 3072 + h * 192;
  const bf16_t* kp = kbuf + (size_t)b * 2048 * 3072 + h * 192;
  const bf16_t* vp = vt + (size_t)bh * 192 * 2048;

  bf16x8 qf[2][6];
#pragma unroll
  for (int kd = 0; kd < 6; kd++) {
    qf[0][kd] = *(const bf16x8*)(qp + (size_t)(rA + l15) * 3072 + kd * 32 + l4 * 8);
    qf[1][kd] = *(const bf16x8*)(qp + (size_t)(rB + l15) * 3072 + kd * 32 + l4 * 8);
  }

  f32x4 o[2][12] = {};
  float mrow[2] = {-__builtin_inff(), -__builtin_inff()};
  float lrow[2] = {0.0f, 0.0f};

  const float scale = 0.07216878364870322f;  // 1/sqrt(192)
  const float THR = 7.0f;                    // defer-max threshold
  const int src0 = l15 + ((l4 & 1) << 5);
  const int src1 = src0 + 16;
  const bool hibank = (l4 & 2) != 0;

#define STAGE_K(KT)                                                                 \
  {                                                                                 \
    const int k0s = (KT) * 64;                                                      \
    _Pragma("unroll")                                                               \
    for (int r = 0; r < 6; r++) {                                                   \
      int i = r * 256 + tid;                                                        \
      int row = i / 24, cc = i % 24;                                                \
      int g = cc - (row & 7) * 3;                                                   \
      if (g < 0) g += 24;                                                           \
      gload_lds16(kp + (size_t)(k0s + row) * 3072 + g * 8,                          \
                  (char*)&sK[0][0] + (size_t)(r * 256 + w * 64) * 16);              \
    }                                                                               \
  }
#define STAGE_V(KT, VB)                                                             \
  {                                                                                 \
    const int k0s = (KT) * 64;                                                      \
    _Pragma("unroll")                                                               \
    for (int r = 0; r < 6; r++) {                                                   \
      int i = r * 256 + tid;                                                        \
      int d = i >> 3, cc = i & 7;                                                   \
      gload_lds16(vp + (size_t)d * 2048 + k0s + (cc ^ (d & 7)) * 8,                 \
                  (char*)&sV[VB][0][0] + (size_t)(r * 256 + w * 64) * 16);          \
    }                                                                               \
  }

  STAGE_K(0)
  STAGE_V(0, 0)
  __syncthreads();  // vmcnt(0) drained -> tile 0 ready

  for (int kt = 0; kt < nkt; kt++) {
    const int bb = kt & 1;
    const int k0 = kt * 64;
    const bool act_a = (kt <= tgA);

    // S^T = K Q^T  (swapped operands); sub-B always active (kt <= nkt-1)
    f32x4 s[2][4] = {};
#pragma unroll
    for (int kd = 0; kd < 6; kd++) {
      bf16x8 bk[4];
#pragma unroll
      for (int nf = 0; nf < 4; nf++) {
        int row = nf * 16 + l15;
        int cl = kd * 4 + l4 + (row & 7) * 3;
        if (cl >= 24) cl -= 24;
        bk[nf] = *(const bf16x8*)(&sK[row][cl * 8]);
      }
#pragma unroll
      for (int nf = 0; nf < 4; nf++)
        s[1][nf] = MFMA16(bk[nf], qf[1][kd], s[1][nf]);
      if (act_a) {
#pragma unroll
        for (int nf = 0; nf < 4; nf++)
          s[0][nf] = MFMA16(bk[nf], qf[0][kd], s[0][nf]);
      }
    }

    __syncthreads();  // all waves done reading sK
    if (kt + 1 < nkt) {
      STAGE_K(kt + 1)
      STAGE_V(kt + 1, bb ^ 1)
    }

    bf16x8 pa[2][2] = {};

#define SOFTMAX_CHUNK(c, rbase, tg)                                                    \
    {                                                                                  \
      const bool diag = (kt == (tg));                                                  \
      _Pragma("unroll")                                                                \
      for (int nf = 0; nf < 4; nf++)                                                   \
        _Pragma("unroll")                                                              \
        for (int r = 0; r < 4; r++) {                                                  \
          float sv = s[c][nf][r] * scale;                                              \
          if (diag) {                                                                  \
            int ktok = k0 + nf * 16 + l4 * 4 + r;                                      \
            if (ktok > (rbase) + l15) sv = -__builtin_inff();                          \
          }                                                                            \
          s[c][nf][r] = sv;                                                            \
        }                                                                              \
      float m_in = s[c][0][0];                                                         \
      _Pragma("unroll")                                                                \
      for (int nf = 0; nf < 4; nf++)                                                   \
        _Pragma("unroll")                                                              \
        for (int r = 0; r < 4; r++)                                                    \
          if (nf | r) m_in = fmaxf(m_in, s[c][nf][r]);                                 \
      m_in = fmaxf(m_in, __shfl_xor(m_in, 16));                                        \
      m_in = fmaxf(m_in, __shfl_xor(m_in, 32));                                        \
      if (!__all(m_in - mrow[c] <= THR)) {                                             \
        float mn = fmaxf(mrow[c], m_in);                                               \
        float alpha = __expf(mrow[c] - mn);                                            \
        mrow[c] = mn;                                                                  \
        lrow[c] *= alpha;                                                              \
        f32x4 av;                                                                      \
        _Pragma("unroll")                                                              \
        for (int r = 0; r < 4; r++) av[r] = __shfl(alpha, l4 * 4 + r);                 \
        _Pragma("unroll")                                                              \
        for (int nf2 = 0; nf2 < 12; nf2++) o[c][nf2] *= av;                            \
      }                                                                                \
      float rs = 0.0f;                                                                 \
      _Pragma("unroll")                                                                \
      for (int nf = 0; nf < 4; nf++)                                                   \
        _Pragma("unroll")                                                              \
        for (int r = 0; r < 4; r++) {                                                  \
          float pv = __expf(s[c][nf][r] - mrow[c]);                                    \
          s[c][nf][r] = pv;                                                            \
          rs += pv;                                                                    \
        }                                                                              \
      rs += __shfl_xor(rs, 16);                                                        \
      rs += __shfl_xor(rs, 32);                                                        \
      lrow[c] += rs;                                                                   \
      uint32_t wq[8];                                                                  \
      _Pragma("unroll")                                                                \
      for (int nf = 0; nf < 4; nf++) {                                                 \
        wq[nf * 2 + 0] = pkbf(s[c][nf][0], s[c][nf][1]);                               \
        wq[nf * 2 + 1] = pkbf(s[c][nf][2], s[c][nf][3]);                               \
      }                                                                                \
      _Pragma("unroll")                                                                \
      for (int ks = 0; ks < 2; ks++) {                                                 \
        uint32_t A0 = __shfl(wq[(2 * ks) * 2 + 0], src0);                              \
        uint32_t A1 = __shfl(wq[(2 * ks) * 2 + 1], src0);                              \
        uint32_t B0 = __shfl(wq[(2 * ks + 1) * 2 + 0], src0);                          \
        uint32_t B1 = __shfl(wq[(2 * ks + 1) * 2 + 1], src0);                          \
        uint32_t C0w = __shfl(wq[(2 * ks) * 2 + 0], src1);                             \
        uint32_t C1w = __shfl(wq[(2 * ks) * 2 + 1], src1);                             \
        uint32_t D0 = __shfl(wq[(2 * ks + 1) * 2 + 0], src1);                          \
        uint32_t D1 = __shfl(wq[(2 * ks + 1) * 2 + 1], src1);                          \
        union { uint32_t u[4]; bf16x8 v; } fr;                                         \
        fr.u[0] = hibank ? B0 : A0;                                                    \
        fr.u[1] = hibank ? B1 : A1;                                                    \
        fr.u[2] = hibank ? D0 : C0w;                                                   \
        fr.u[3] = hibank ? D1 : C1w;                                                   \
        pa[c][ks] = fr.v;                                                              \
      }                                                                                \
    }

    SOFTMAX_CHUNK(1, rB, nkt - 1)
    if (act_a) SOFTMAX_CHUNK(0, rA, tgA)
#undef SOFTMAX_CHUNK

    // O += P V   (A = in-register P frags, B = V from LDS)
#pragma unroll
    for (int ks = 0; ks < 2; ks++) {
#pragma unroll
      for (int nf2 = 0; nf2 < 12; nf2++) {
        int d = nf2 * 16 + l15;
        int cl = (ks * 4 + l4) ^ (d & 7);
        bf16x8 vb = *(const bf16x8*)(&sV[bb][d][cl * 8]);
        o[1][nf2] = MFMA16(pa[1][ks], vb, o[1][nf2]);
        if (act_a) o[0][nf2] = MFMA16(pa[0][ks], vb, o[0][nf2]);
      }
    }

    __syncthreads();  // drains vmcnt -> sK/sV[bb^1] hold tile kt+1; PV readers done
  }
#undef STAGE_K
#undef STAGE_V

  // epilogue: O/l -> ao (b*T+q, h*192+d), both sub-chunks; l lives at lane l15=q
#pragma unroll
  for (int mf = 0; mf < 2; mf++) {
    const int rbase = (mf == 0) ? rA : rB;
#pragma unroll
    for (int r = 0; r < 4; r++) {
      float lv = __shfl(lrow[mf], l4 * 4 + r);
      float inv = 1.0f / lv;
      int qrow = rbase + l4 * 4 + r;
#pragma unroll
      for (int nf2 = 0; nf2 < 12; nf2++) {
        int d = nf2 * 16 + l15;
        ao[(size_t)(b * 2048 + qrow) * 3072 + h * 192 + d] = (bf16_t)(o[mf][nf2][r] * inv);
      }
    }
  }
}

// ----------------------------------------------------------------
extern "C" void kernel_launch(void* const* d_in, const int* in_sizes, int n_in,
                              void* d_out, int out_size, void* d_ws, size_t ws_size,
                              hipStream_t stream) {
  const float* x       = (const float*)d_in[0];
  const float* wq_down = (const float*)d_in[1];
  const float* wq_up   = (const float*)d_in[2];
  const float* wq_rope = (const float*)d_in[3];
  const float* wkv_down= (const float*)d_in[4];
  const float* wk_up   = (const float*)d_in[5];
  const float* wv_up   = (const float*)d_in[6];
  const float* wk_rope = (const float*)d_in[7];
  const float* wo      = (const float*)d_in[8];
  float* out = (float*)d_out;

  char* p = (char*)d_ws;
  auto take = [&](size_t elems) { bf16_t* r = (bf16_t*)p; p += elems * 2; return r; };
  bf16_t* xb    = take(4096ull * 2048);
  bf16_t* fw1   = take(3328ull * 2048);  // [wq_down(768) | wkv_down(512) | wq_rope(1024) | wk_rope(1024)]^T
  bf16_t* wqu_t = take(2048ull * 768);
  bf16_t* fw2   = take(5120ull * 512);   // [wk_up(2048) | wv_up(3072)]^T
  bf16_t* wo_t  = take(2048ull * 3072);
  bf16_t* qkvd  = take(4096ull * 1280);  // [q_down(768) | latent(512)]
  bf16_t* qbuf  = take(4096ull * 3072);
  bf16_t* kbuf  = take(4096ull * 3072);
  bf16_t* vbuf  = take(4096ull * 3072);
  bf16_t* vt    = take(4096ull * 3072);
  bf16_t* ao    = vbuf;  // v row-major dead after transpose_v; reuse for attention out

  dim3 tb(32, 8);
  cvt_f32_to_bf16<<<8192, 256, 0, stream>>>(x, xb);
  transpose_w<<<dim3(24, 64), tb, 0, stream>>>(wq_down,  fw1,                 2048, 768);
  transpose_w<<<dim3(16, 64), tb, 0, stream>>>(wkv_down, fw1 + 768ull * 2048, 2048, 512);
  transpose_w<<<dim3(32, 64), tb, 0, stream>>>(wq_rope,  fw1 + 1280ull * 2048,2048, 1024);
  transpose_w<<<dim3(32, 64), tb, 0, stream>>>(wk_rope,  fw1 + 2304ull * 2048,2048, 1024);
  transpose_w<<<dim3(64, 24), tb, 0, stream>>>(wq_up,    wqu_t,               768, 2048);
  transpose_w<<<dim3(64, 16), tb, 0, stream>>>(wk_up,    fw2,                 512, 2048);
  transpose_w<<<dim3(96, 16), tb, 0, stream>>>(wv_up,    fw2 + 2048ull * 512, 512, 3072);
  transpose_w<<<dim3(64, 96), tb, 0, stream>>>(wo,       wo_t,                3072, 2048);

  gemm_bt<4><<<dim3(26, 32), 256, 0, stream>>>(xb, 2048, fw1, qkvd, qbuf, kbuf, 2048, 0);
  gemm_bt<2><<<dim3(16, 32), 256, 0, stream>>>(qkvd, 1280, wqu_t, qbuf, nullptr, nullptr, 768, 0);
  gemm_bt<5><<<dim3(40, 32), 256, 0, stream>>>(qkvd + 768, 1280, fw2, kbuf, vbuf, nullptr, 512, 0);

  rope_inplace<<<8192, 256, 0, stream>>>(qbuf);
  rope_inplace<<<8192, 256, 0, stream>>>(kbuf);
  transpose_v_kernel<<<dim3(64, 6, 32), tb, 0, stream>>>(vbuf, vt);

  attn_kernel<<<512, 256, 0, stream>>>(qbuf, kbuf, vt, ao);

  gemm_bt<1><<<dim3(16, 32), 256, 0, stream>>>(ao, 3072, wo_t, out, nullptr, nullptr, 3072, 2048);
}

// Round 7
// 384.019 us; speedup vs baseline: 1.1012x; 1.1012x over previous
//
#include <hip/hip_runtime.h>
#include <hip/hip_bf16.h>
#include <cstdint>
#include <cstddef>

typedef __bf16 bf16_t;
typedef __bf16 bf16x8 __attribute__((ext_vector_type(8)));
typedef float f32x4 __attribute__((ext_vector_type(4)));

#define MFMA16(a, b, c) __builtin_amdgcn_mfma_f32_16x16x32_bf16((a), (b), (c), 0, 0, 0)

__device__ __forceinline__ void gload_lds16(const void* g, void* l) {
  __builtin_amdgcn_global_load_lds((__attribute__((address_space(1))) void*)(g),
                                   (__attribute__((address_space(3))) void*)(l),
                                   16, 0, 0);
}

__device__ __forceinline__ uint32_t pkbf(float lo, float hi) {
  union { bf16_t h[2]; uint32_t u; } u2;
  u2.h[0] = (bf16_t)lo; u2.h[1] = (bf16_t)hi;
  return u2.u;
}

// ---------------------------------------------------------------- cvt x fp32->bf16
__global__ __launch_bounds__(256) void cvt_f32_to_bf16(const float* __restrict__ in,
                                                       bf16_t* __restrict__ out) {
  size_t i = ((size_t)blockIdx.x * 256 + threadIdx.x) * 4;
  float4 v = *(const float4*)(in + i);
  bf16_t o[4] = {(bf16_t)v.x, (bf16_t)v.y, (bf16_t)v.z, (bf16_t)v.w};
  *(uint2*)(out + i) = *(uint2*)o;
}

// ---------------------------------------------------------------- weight transpose fp32 (R,C) -> bf16 (C,R)
__global__ __launch_bounds__(256) void transpose_w(const float* __restrict__ in,
                                                   bf16_t* __restrict__ out, int R, int C) {
  __shared__ bf16_t tile[32][33];
  int c0 = blockIdx.x * 32, r0 = blockIdx.y * 32;
  int tx = threadIdx.x, ty = threadIdx.y;
#pragma unroll
  for (int s = 0; s < 4; s++) {
    int r = ty + s * 8;
    tile[r][tx] = (bf16_t)in[(size_t)(r0 + r) * C + c0 + tx];
  }
  __syncthreads();
#pragma unroll
  for (int s = 0; s < 4; s++) {
    int r = ty + s * 8;
    out[(size_t)(c0 + r) * R + r0 + tx] = tile[tx][r];
  }
}

// ---------------------------------------------------------------- v (4096,3072) -> vt (b,h,192,2048)
__global__ __launch_bounds__(256) void transpose_v_kernel(const bf16_t* __restrict__ v,
                                                          bf16_t* __restrict__ vt) {
  __shared__ bf16_t tile[32][33];
  int bh = blockIdx.z;
  int t0 = blockIdx.x * 32, d0 = blockIdx.y * 32;
  int tx = threadIdx.x, ty = threadIdx.y;
  const bf16_t* src = v + (size_t)(bh >> 4) * 2048 * 3072 + (bh & 15) * 192;
#pragma unroll
  for (int s = 0; s < 4; s++) {
    int t = ty + s * 8;
    tile[t][tx] = src[(size_t)(t0 + t) * 3072 + d0 + tx];
  }
  __syncthreads();
  bf16_t* dst = vt + (size_t)bh * 192 * 2048;
#pragma unroll
  for (int s = 0; s < 4; s++) {
    int d = ty + s * 8;
    dst[(size_t)(d0 + d) * 2048 + t0 + tx] = tile[tx][d];
  }
}

// ---------------------------------------------------------------- rope in-place on packed (4096, 16*192) buffer
__global__ __launch_bounds__(256) void rope_inplace(bf16_t* __restrict__ buf) {
  int idx = blockIdx.x * 256 + threadIdx.x;
  int j = idx & 31;
  int h = (idx >> 5) & 15;
  int row = idx >> 9;           // 0..4095
  int t = row & 2047;
  size_t base = (size_t)row * 3072 + h * 192 + 128;
  float inv = expf(-(float)j * 0.28782313662425574f);
  float ang = (float)t * inv;
  float c, s;
  sincosf(ang, &s, &c);
  float x1 = (float)buf[base + j];
  float x2 = (float)buf[base + j + 32];
  buf[base + j]      = (bf16_t)(x1 * c - x2 * s);
  buf[base + j + 32] = (bf16_t)(x1 * s + x2 * c);
}

// ---------------------------------------------------------------- GEMM: C = A(M,lda) [:, :K] * Bt(N,K)^T
template <int MODE>
__global__ __launch_bounds__(256) void gemm_bt(const bf16_t* __restrict__ A, int lda,
                                               const bf16_t* __restrict__ Bt,
                                               void* __restrict__ C0, void* __restrict__ C1,
                                               void* __restrict__ C2, int K, int ldc) {
  __shared__ __align__(16) bf16_t sA[128 * 64];
  __shared__ __align__(16) bf16_t sB[128 * 64];
  const int tid = threadIdx.x;
  const int l = tid & 63, w = tid >> 6;
  const int l15 = l & 15, l4 = l >> 4;
  const int wr = w >> 1, wc = w & 1;
  const int m0 = blockIdx.y * 128, n0 = blockIdx.x * 128;

  f32x4 acc[4][4] = {};

  for (int kt = 0; kt < K; kt += 64) {
#pragma unroll
    for (int r = 0; r < 4; r++) {
      int i = r * 256 + tid;
      int row = i >> 3, cl = i & 7;
      int cg = cl ^ (row & 7);  // pre-swizzled global source, linear LDS dest
      const bf16_t* srcA = A + (size_t)(m0 + row) * lda + kt + cg * 8;
      const bf16_t* srcB = Bt + (size_t)(n0 + row) * K + kt + cg * 8;
      char* dstA = (char*)sA + (size_t)(r * 256 + w * 64) * 16;
      char* dstB = (char*)sB + (size_t)(r * 256 + w * 64) * 16;
      gload_lds16(srcA, dstA);
      gload_lds16(srcB, dstB);
    }
    __syncthreads();
#pragma unroll
    for (int ks = 0; ks < 2; ks++) {
      bf16x8 af[4], bfr[4];
#pragma unroll
      for (int mf = 0; mf < 4; mf++) {
        int row = wr * 64 + mf * 16 + l15;
        int cl = (ks * 4 + l4) ^ (row & 7);
        af[mf] = *(const bf16x8*)(sA + row * 64 + cl * 8);
      }
#pragma unroll
      for (int nf = 0; nf < 4; nf++) {
        int row = wc * 64 + nf * 16 + l15;
        int cl = (ks * 4 + l4) ^ (row & 7);
        bfr[nf] = *(const bf16x8*)(sB + row * 64 + cl * 8);
      }
#pragma unroll
      for (int mf = 0; mf < 4; mf++)
#pragma unroll
        for (int nf = 0; nf < 4; nf++)
          acc[mf][nf] = MFMA16(af[mf], bfr[nf], acc[mf][nf]);
    }
    __syncthreads();
  }

#pragma unroll
  for (int mf = 0; mf < 4; mf++)
#pragma unroll
    for (int nf = 0; nf < 4; nf++)
#pragma unroll
      for (int r = 0; r < 4; r++) {
        int m = m0 + wr * 64 + mf * 16 + l4 * 4 + r;
        int n = n0 + wc * 64 + nf * 16 + l15;
        float v = acc[mf][nf][r];
        if constexpr (MODE == 1) {
          ((float*)C0)[(size_t)m * ldc + n] = v;
        } else if constexpr (MODE == 2) {
          ((bf16_t*)C0)[(size_t)m * 3072 + (n >> 7) * 192 + (n & 127)] = (bf16_t)v;
        } else if constexpr (MODE == 4) {
          if (n < 1280) {
            ((bf16_t*)C0)[(size_t)m * 1280 + n] = (bf16_t)v;
          } else if (n < 2304) {
            int nn = n - 1280;
            ((bf16_t*)C1)[(size_t)m * 3072 + (nn >> 6) * 192 + 128 + (nn & 63)] = (bf16_t)v;
          } else {
            int nn = n - 2304;
            ((bf16_t*)C2)[(size_t)m * 3072 + (nn >> 6) * 192 + 128 + (nn & 63)] = (bf16_t)v;
          }
        } else {  // MODE 5
          if (n < 2048) {
            ((bf16_t*)C0)[(size_t)m * 3072 + (n >> 7) * 192 + (n & 127)] = (bf16_t)v;
          } else {
            ((bf16_t*)C1)[(size_t)m * 3072 + (n - 2048)] = (bf16_t)v;
          }
        }
      }
}

// ---------------------------------------------------------------- flash attention (causal)
// R5 structure (8 waves / 512 threads, pairs (c,31-c) of 128-row chunks) but the
// K/V double buffers are STATICALLY DISTINCT __shared__ objects with a 2x-unrolled
// loop, so alias analysis can prove stage(sK1/sV1) is independent of reads(sK0/sV0)
// and the global_load_lds prefetch genuinely overlaps compute (no mid-tile vmcnt).
__global__ __launch_bounds__(512, 2) void attn_kernel(const bf16_t* __restrict__ q,
                                                      const bf16_t* __restrict__ kbuf,
                                                      const bf16_t* __restrict__ vt,
                                                      bf16_t* __restrict__ ao) {
  __shared__ __align__(16) bf16_t sK0[64][192];  // perm-24 swizzle
  __shared__ __align__(16) bf16_t sK1[64][192];
  __shared__ __align__(16) bf16_t sV0[192][64];  // xor-8 chunk swizzle
  __shared__ __align__(16) bf16_t sV1[192][64];

  const int tid = threadIdx.x, l = tid & 63, w = tid >> 6;
  const int l15 = l & 15, l4 = (l >> 4) & 3;
  const int bh = blockIdx.x & 31;            // same-bh blocks share an XCD (i%8 preserved)
  const int c = blockIdx.x >> 5;             // pair index 0..7
  const int b = bh >> 4, h = bh & 15;
  const int ca = c, cb = 15 - c;             // 128-row chunks
  const int ra = ca * 128 + w * 16;
  const int rb = cb * 128 + w * 16;
  const int tga = 2 * ca + (w >> 2);         // diag k-tile for this wave's chunk-a rows
  const int tgb = 2 * cb + (w >> 2);

  const bf16_t* qp = q + (size_t)b * 2048 * 3072 + h * 192;
  const bf16_t* kp = kbuf + (size_t)b * 2048 * 3072 + h * 192;
  const bf16_t* vp = vt + (size_t)bh * 192 * 2048;

  bf16x8 qf[2][6];
#pragma unroll
  for (int kd = 0; kd < 6; kd++) {
    qf[0][kd] = *(const bf16x8*)(qp + (size_t)(ra + l15) * 3072 + kd * 32 + l4 * 8);
    qf[1][kd] = *(const bf16x8*)(qp + (size_t)(rb + l15) * 3072 + kd * 32 + l4 * 8);
  }

  f32x4 o[2][12] = {};
  float mrow[2] = {-__builtin_inff(), -__builtin_inff()};
  float lrow[2] = {0.0f, 0.0f};

  const float scale = 0.07216878364870322f;  // 1/sqrt(192)
  const float THR = 7.0f;                    // defer-max threshold
  const int nkt = 2 * cb + 2;                // always even
  const int src0 = l15 + ((l4 & 1) << 5);
  const int src1 = src0 + 16;
  const bool hibank = (l4 & 2) != 0;

#define STAGE(SK, SV, KT)                                                           \
  {                                                                                 \
    const int k0s = (KT) * 64;                                                      \
    _Pragma("unroll")                                                               \
    for (int r = 0; r < 3; r++) {                                                   \
      int i = r * 512 + tid;                                                        \
      int row = i / 24, cc = i % 24;                                                \
      int g = cc - (row & 7) * 3;                                                   \
      if (g < 0) g += 24;                                                           \
      gload_lds16(kp + (size_t)(k0s + row) * 3072 + g * 8,                          \
                  (char*)&SK[0][0] + (size_t)(r * 512 + w * 64) * 16);              \
    }                                                                               \
    _Pragma("unroll")                                                               \
    for (int r = 0; r < 3; r++) {                                                   \
      int i = r * 512 + tid;                                                        \
      int d = i >> 3, cc = i & 7;                                                   \
      gload_lds16(vp + (size_t)d * 2048 + k0s + (cc ^ (d & 7)) * 8,                 \
                  (char*)&SV[0][0] + (size_t)(r * 512 + w * 64) * 16);              \
    }                                                                               \
  }

#define SOFTMAX_CHUNK(c, rbase, tg)                                                    \
    {                                                                                  \
      const bool diag = (kt == (tg));                                                  \
      _Pragma("unroll")                                                                \
      for (int nf = 0; nf < 4; nf++)                                                   \
        _Pragma("unroll")                                                              \
        for (int r = 0; r < 4; r++) {                                                  \
          float sv = s[c][nf][r] * scale;                                              \
          if (diag) {                                                                  \
            int ktok = k0 + nf * 16 + l4 * 4 + r;                                      \
            if (ktok > (rbase) + l15) sv = -__builtin_inff();                          \
          }                                                                            \
          s[c][nf][r] = sv;                                                            \
        }                                                                              \
      float m_in = s[c][0][0];                                                         \
      _Pragma("unroll")                                                                \
      for (int nf = 0; nf < 4; nf++)                                                   \
        _Pragma("unroll")                                                              \
        for (int r = 0; r < 4; r++)                                                    \
          if (nf | r) m_in = fmaxf(m_in, s[c][nf][r]);                                 \
      m_in = fmaxf(m_in, __shfl_xor(m_in, 16));                                        \
      m_in = fmaxf(m_in, __shfl_xor(m_in, 32));                                        \
      if (!__all(m_in - mrow[c] <= THR)) {                                             \
        float mn = fmaxf(mrow[c], m_in);                                               \
        float alpha = __expf(mrow[c] - mn);                                            \
        mrow[c] = mn;                                                                  \
        lrow[c] *= alpha;                                                              \
        f32x4 av;                                                                      \
        _Pragma("unroll")                                                              \
        for (int r = 0; r < 4; r++) av[r] = __shfl(alpha, l4 * 4 + r);                 \
        _Pragma("unroll")                                                              \
        for (int nf2 = 0; nf2 < 12; nf2++) o[c][nf2] *= av;                            \
      }                                                                                \
      float rs = 0.0f;                                                                 \
      _Pragma("unroll")                                                                \
      for (int nf = 0; nf < 4; nf++)                                                   \
        _Pragma("unroll")                                                              \
        for (int r = 0; r < 4; r++) {                                                  \
          float pv = __expf(s[c][nf][r] - mrow[c]);                                    \
          s[c][nf][r] = pv;                                                            \
          rs += pv;                                                                    \
        }                                                                              \
      rs += __shfl_xor(rs, 16);                                                        \
      rs += __shfl_xor(rs, 32);                                                        \
      lrow[c] += rs;                                                                   \
      uint32_t wq[8];                                                                  \
      _Pragma("unroll")                                                                \
      for (int nf = 0; nf < 4; nf++) {                                                 \
        wq[nf * 2 + 0] = pkbf(s[c][nf][0], s[c][nf][1]);                               \
        wq[nf * 2 + 1] = pkbf(s[c][nf][2], s[c][nf][3]);                               \
      }                                                                                \
      _Pragma("unroll")                                                                \
      for (int ks = 0; ks < 2; ks++) {                                                 \
        uint32_t A0 = __shfl(wq[(2 * ks) * 2 + 0], src0);                              \
        uint32_t A1 = __shfl(wq[(2 * ks) * 2 + 1], src0);                              \
        uint32_t B0 = __shfl(wq[(2 * ks + 1) * 2 + 0], src0);                          \
        uint32_t B1 = __shfl(wq[(2 * ks + 1) * 2 + 1], src0);                          \
        uint32_t C0w = __shfl(wq[(2 * ks) * 2 + 0], src1);                             \
        uint32_t C1w = __shfl(wq[(2 * ks) * 2 + 1], src1);                             \
        uint32_t D0 = __shfl(wq[(2 * ks + 1) * 2 + 0], src1);                          \
        uint32_t D1 = __shfl(wq[(2 * ks + 1) * 2 + 1], src1);                          \
        union { uint32_t u[4]; bf16x8 v; } fr;                                         \
        fr.u[0] = hibank ? B0 : A0;                                                    \
        fr.u[1] = hibank ? B1 : A1;                                                    \
        fr.u[2] = hibank ? D0 : C0w;                                                   \
        fr.u[3] = hibank ? D1 : C1w;                                                   \
        pa[c][ks] = fr.v;                                                              \
      }                                                                                \
    }

#define TILE_BODY(SK, SV, KT)                                                          \
  {                                                                                    \
    const int kt = (KT);                                                               \
    const int k0 = kt * 64;                                                            \
    const bool act_a = (kt <= tga);                                                    \
    const bool act_b = (kt <= tgb);                                                    \
    f32x4 s[2][4] = {};                                                                \
    _Pragma("unroll")                                                                  \
    for (int kd = 0; kd < 6; kd++) {                                                   \
      bf16x8 bk[4];                                                                    \
      _Pragma("unroll")                                                                \
      for (int nf = 0; nf < 4; nf++) {                                                 \
        int row = nf * 16 + l15;                                                       \
        int cl = kd * 4 + l4 + (row & 7) * 3;                                          \
        if (cl >= 24) cl -= 24;                                                        \
        bk[nf] = *(const bf16x8*)(&SK[row][cl * 8]);                                   \
      }                                                                                \
      if (act_b) {                                                                     \
        _Pragma("unroll")                                                              \
        for (int nf = 0; nf < 4; nf++)                                                 \
          s[1][nf] = MFMA16(bk[nf], qf[1][kd], s[1][nf]);                              \
      }                                                                                \
      if (act_a) {                                                                     \
        _Pragma("unroll")                                                              \
        for (int nf = 0; nf < 4; nf++)                                                 \
          s[0][nf] = MFMA16(bk[nf], qf[0][kd], s[0][nf]);                              \
      }                                                                                \
    }                                                                                  \
    bf16x8 pa[2][2] = {};                                                              \
    if (act_b) SOFTMAX_CHUNK(1, rb, tgb)                                               \
    if (act_a) SOFTMAX_CHUNK(0, ra, tga)                                               \
    _Pragma("unroll")                                                                  \
    for (int ks = 0; ks < 2; ks++) {                                                   \
      _Pragma("unroll")                                                                \
      for (int nf2 = 0; nf2 < 12; nf2++) {                                             \
        int d = nf2 * 16 + l15;                                                        \
        int cl = (ks * 4 + l4) ^ (d & 7);                                              \
        bf16x8 vb = *(const bf16x8*)(&SV[d][cl * 8]);                                  \
        if (act_b) o[1][nf2] = MFMA16(pa[1][ks], vb, o[1][nf2]);                       \
        if (act_a) o[0][nf2] = MFMA16(pa[0][ks], vb, o[0][nf2]);                       \
      }                                                                                \
    }                                                                                  \
  }

  STAGE(sK0, sV0, 0)
  __syncthreads();  // tile 0 ready

  for (int kt0 = 0; kt0 < nkt; kt0 += 2) {
    // even tile (in sK0/sV0); prefetch odd tile into sK1/sV1 (distinct objects!)
    STAGE(sK1, sV1, kt0 + 1)
    TILE_BODY(sK0, sV0, kt0)
    __syncthreads();  // drains stage(kt0+1); covered by the compute above
    // odd tile (in sK1/sV1); prefetch next even tile into sK0/sV0
    if (kt0 + 2 < nkt) STAGE(sK0, sV0, kt0 + 2)
    TILE_BODY(sK1, sV1, kt0 + 1)
    __syncthreads();
  }
#undef STAGE
#undef SOFTMAX_CHUNK
#undef TILE_BODY

  // epilogue: O/l -> ao (b*T+q, h*192+d), both chunks; l lives at lane l15=q
#pragma unroll
  for (int mf = 0; mf < 2; mf++) {
    const int rbase = (mf == 0) ? ra : rb;
#pragma unroll
    for (int r = 0; r < 4; r++) {
      float lv = __shfl(lrow[mf], l4 * 4 + r);
      float inv = 1.0f / lv;
      int qrow = rbase + l4 * 4 + r;
#pragma unroll
      for (int nf2 = 0; nf2 < 12; nf2++) {
        int d = nf2 * 16 + l15;
        ao[(size_t)(b * 2048 + qrow) * 3072 + h * 192 + d] = (bf16_t)(o[mf][nf2][r] * inv);
      }
    }
  }
}

// ----------------------------------------------------------------
extern "C" void kernel_launch(void* const* d_in, const int* in_sizes, int n_in,
                              void* d_out, int out_size, void* d_ws, size_t ws_size,
                              hipStream_t stream) {
  const float* x       = (const float*)d_in[0];
  const float* wq_down = (const float*)d_in[1];
  const float* wq_up   = (const float*)d_in[2];
  const float* wq_rope = (const float*)d_in[3];
  const float* wkv_down= (const float*)d_in[4];
  const float* wk_up   = (const float*)d_in[5];
  const float* wv_up   = (const float*)d_in[6];
  const float* wk_rope = (const float*)d_in[7];
  const float* wo      = (const float*)d_in[8];
  float* out = (float*)d_out;

  char* p = (char*)d_ws;
  auto take = [&](size_t elems) { bf16_t* r = (bf16_t*)p; p += elems * 2; return r; };
  bf16_t* xb    = take(4096ull * 2048);
  bf16_t* fw1   = take(3328ull * 2048);  // [wq_down(768) | wkv_down(512) | wq_rope(1024) | wk_rope(1024)]^T
  bf16_t* wqu_t = take(2048ull * 768);
  bf16_t* fw2   = take(5120ull * 512);   // [wk_up(2048) | wv_up(3072)]^T
  bf16_t* wo_t  = take(2048ull * 3072);
  bf16_t* qkvd  = take(4096ull * 1280);  // [q_down(768) | latent(512)]
  bf16_t* qbuf  = take(4096ull * 3072);
  bf16_t* kbuf  = take(4096ull * 3072);
  bf16_t* vbuf  = take(4096ull * 3072);
  bf16_t* vt    = take(4096ull * 3072);
  bf16_t* ao    = vbuf;  // v row-major dead after transpose_v; reuse for attention out

  dim3 tb(32, 8);
  cvt_f32_to_bf16<<<8192, 256, 0, stream>>>(x, xb);
  transpose_w<<<dim3(24, 64), tb, 0, stream>>>(wq_down,  fw1,                 2048, 768);
  transpose_w<<<dim3(16, 64), tb, 0, stream>>>(wkv_down, fw1 + 768ull * 2048, 2048, 512);
  transpose_w<<<dim3(32, 64), tb, 0, stream>>>(wq_rope,  fw1 + 1280ull * 2048,2048, 1024);
  transpose_w<<<dim3(32, 64), tb, 0, stream>>>(wk_rope,  fw1 + 2304ull * 2048,2048, 1024);
  transpose_w<<<dim3(64, 24), tb, 0, stream>>>(wq_up,    wqu_t,               768, 2048);
  transpose_w<<<dim3(64, 16), tb, 0, stream>>>(wk_up,    fw2,                 512, 2048);
  transpose_w<<<dim3(96, 16), tb, 0, stream>>>(wv_up,    fw2 + 2048ull * 512, 512, 3072);
  transpose_w<<<dim3(64, 96), tb, 0, stream>>>(wo,       wo_t,                3072, 2048);

  gemm_bt<4><<<dim3(26, 32), 256, 0, stream>>>(xb, 2048, fw1, qkvd, qbuf, kbuf, 2048, 0);
  gemm_bt<2><<<dim3(16, 32), 256, 0, stream>>>(qkvd, 1280, wqu_t, qbuf, nullptr, nullptr, 768, 0);
  gemm_bt<5><<<dim3(40, 32), 256, 0, stream>>>(qkvd + 768, 1280, fw2, kbuf, vbuf, nullptr, 512, 0);

  rope_inplace<<<8192, 256, 0, stream>>>(qbuf);
  rope_inplace<<<8192, 256, 0, stream>>>(kbuf);
  transpose_v_kernel<<<dim3(64, 6, 32), tb, 0, stream>>>(vbuf, vt);

  attn_kernel<<<256, 512, 0, stream>>>(qbuf, kbuf, vt, ao);

  gemm_bt<1><<<dim3(16, 32), 256, 0, stream>>>(ao, 3072, wo_t, out, nullptr, nullptr, 3072, 2048);
}

// Round 8
// 373.349 us; speedup vs baseline: 1.1327x; 1.0286x over previous
//
#include <hip/hip_runtime.h>
#include <hip/hip_bf16.h>
#include <cstdint>
#include <cstddef>

typedef __bf16 bf16_t;
typedef __bf16 bf16x8 __attribute__((ext_vector_type(8)));
typedef float f32x4 __attribute__((ext_vector_type(4)));

#define MFMA16(a, b, c) __builtin_amdgcn_mfma_f32_16x16x32_bf16((a), (b), (c), 0, 0, 0)

__device__ __forceinline__ void gload_lds16(const void* g, void* l) {
  __builtin_amdgcn_global_load_lds((__attribute__((address_space(1))) void*)(g),
                                   (__attribute__((address_space(3))) void*)(l),
                                   16, 0, 0);
}

__device__ __forceinline__ uint32_t pkbf(float lo, float hi) {
  union { bf16_t h[2]; uint32_t u; } u2;
  u2.h[0] = (bf16_t)lo; u2.h[1] = (bf16_t)hi;
  return u2.u;
}

// ---------------------------------------------------------------- cvt x fp32->bf16
__global__ __launch_bounds__(256) void cvt_f32_to_bf16(const float* __restrict__ in,
                                                       bf16_t* __restrict__ out) {
  size_t i = ((size_t)blockIdx.x * 256 + threadIdx.x) * 4;
  float4 v = *(const float4*)(in + i);
  bf16_t o[4] = {(bf16_t)v.x, (bf16_t)v.y, (bf16_t)v.z, (bf16_t)v.w};
  *(uint2*)(out + i) = *(uint2*)o;
}

// ---------------------------------------------------------------- weight transpose fp32 (R,C) -> bf16 (C,R)
__global__ __launch_bounds__(256) void transpose_w(const float* __restrict__ in,
                                                   bf16_t* __restrict__ out, int R, int C) {
  __shared__ bf16_t tile[32][33];
  int c0 = blockIdx.x * 32, r0 = blockIdx.y * 32;
  int tx = threadIdx.x, ty = threadIdx.y;
#pragma unroll
  for (int s = 0; s < 4; s++) {
    int r = ty + s * 8;
    tile[r][tx] = (bf16_t)in[(size_t)(r0 + r) * C + c0 + tx];
  }
  __syncthreads();
#pragma unroll
  for (int s = 0; s < 4; s++) {
    int r = ty + s * 8;
    out[(size_t)(c0 + r) * R + r0 + tx] = tile[tx][r];
  }
}

// ---------------------------------------------------------------- v (4096,3072) -> vt (b,h,192,2048)
__global__ __launch_bounds__(256) void transpose_v_kernel(const bf16_t* __restrict__ v,
                                                          bf16_t* __restrict__ vt) {
  __shared__ bf16_t tile[32][33];
  int bh = blockIdx.z;
  int t0 = blockIdx.x * 32, d0 = blockIdx.y * 32;
  int tx = threadIdx.x, ty = threadIdx.y;
  const bf16_t* src = v + (size_t)(bh >> 4) * 2048 * 3072 + (bh & 15) * 192;
#pragma unroll
  for (int s = 0; s < 4; s++) {
    int t = ty + s * 8;
    tile[t][tx] = src[(size_t)(t0 + t) * 3072 + d0 + tx];
  }
  __syncthreads();
  bf16_t* dst = vt + (size_t)bh * 192 * 2048;
#pragma unroll
  for (int s = 0; s < 4; s++) {
    int d = ty + s * 8;
    dst[(size_t)(d0 + d) * 2048 + t0 + tx] = tile[tx][d];
  }
}

// ---------------------------------------------------------------- rope in-place on packed (4096, 16*192) buffer
__global__ __launch_bounds__(256) void rope_inplace(bf16_t* __restrict__ buf) {
  int idx = blockIdx.x * 256 + threadIdx.x;
  int j = idx & 31;
  int h = (idx >> 5) & 15;
  int row = idx >> 9;           // 0..4095
  int t = row & 2047;
  size_t base = (size_t)row * 3072 + h * 192 + 128;
  float inv = expf(-(float)j * 0.28782313662425574f);
  float ang = (float)t * inv;
  float c, s;
  sincosf(ang, &s, &c);
  float x1 = (float)buf[base + j];
  float x2 = (float)buf[base + j + 32];
  buf[base + j]      = (bf16_t)(x1 * c - x2 * s);
  buf[base + j + 32] = (bf16_t)(x1 * s + x2 * c);
}

// ---------------------------------------------------------------- GEMM: C = A(M,lda)[:, :K] * Bt(N,K)^T
// 256(M)x128(N) tile, BK=64, 512 thr / 8 waves (wr=w>>1 over M, wc=w&1 over N),
// per-wave 64x64 (4x4 frags of 16x16x32). Double-buffered staging one K-step
// ahead with COUNTED vmcnt(6) + raw s_barrier (no __syncthreads drain-0 in loop).
// K/64 must be even (all call sites: 8,12,32,48).
template <int MODE>
__global__ __launch_bounds__(512, 2) void gemm_bt2(const bf16_t* __restrict__ A, int lda,
                                                   const bf16_t* __restrict__ Bt,
                                                   void* __restrict__ C0, void* __restrict__ C1,
                                                   void* __restrict__ C2, int K, int ldc) {
  __shared__ __align__(16) bf16_t sA0[256 * 64];
  __shared__ __align__(16) bf16_t sB0[128 * 64];
  __shared__ __align__(16) bf16_t sA1[256 * 64];
  __shared__ __align__(16) bf16_t sB1[128 * 64];
  const int tid = threadIdx.x;
  const int l = tid & 63, w = tid >> 6;
  const int l15 = l & 15, l4 = (l >> 4) & 3;
  const int wr = w >> 1, wc = w & 1;
  const int m0 = blockIdx.y * 256, n0 = blockIdx.x * 128;
  const int nt = K >> 6;

  f32x4 acc[4][4] = {};

  // stage tile KT into SA/SB: 4 A-loads + 2 B-loads per thread (6 total)
#define STAGEG(SA, SB, KT)                                                          \
  {                                                                                 \
    const int kts = (KT) * 64;                                                      \
    _Pragma("unroll")                                                               \
    for (int r = 0; r < 4; r++) {                                                   \
      int i = r * 512 + tid;                                                        \
      int row = i >> 3, cl = i & 7;                                                 \
      int cg = cl ^ (row & 7);                                                      \
      gload_lds16(A + (size_t)(m0 + row) * lda + kts + cg * 8,                      \
                  (char*)(SA) + (size_t)(r * 512 + w * 64) * 16);                   \
    }                                                                               \
    _Pragma("unroll")                                                               \
    for (int r = 0; r < 2; r++) {                                                   \
      int i = r * 512 + tid;                                                        \
      int row = i >> 3, cl = i & 7;                                                 \
      int cg = cl ^ (row & 7);                                                      \
      gload_lds16(Bt + (size_t)(n0 + row) * K + kts + cg * 8,                       \
                  (char*)(SB) + (size_t)(r * 512 + w * 64) * 16);                   \
    }                                                                               \
  }

#define GCOMPUTE(SA, SB)                                                            \
  {                                                                                 \
    _Pragma("unroll")                                                               \
    for (int ks = 0; ks < 2; ks++) {                                                \
      bf16x8 af[4], bfr[4];                                                         \
      _Pragma("unroll")                                                             \
      for (int mf = 0; mf < 4; mf++) {                                              \
        int row = wr * 64 + mf * 16 + l15;                                          \
        int cl = (ks * 4 + l4) ^ (row & 7);                                         \
        af[mf] = *(const bf16x8*)((SA) + row * 64 + cl * 8);                        \
      }                                                                             \
      _Pragma("unroll")                                                             \
      for (int nf = 0; nf < 4; nf++) {                                              \
        int row = wc * 64 + nf * 16 + l15;                                          \
        int cl = (ks * 4 + l4) ^ (row & 7);                                         \
        bfr[nf] = *(const bf16x8*)((SB) + row * 64 + cl * 8);                       \
      }                                                                             \
      _Pragma("unroll")                                                             \
      for (int mf = 0; mf < 4; mf++)                                                \
        _Pragma("unroll")                                                           \
        for (int nf = 0; nf < 4; nf++)                                              \
          acc[mf][nf] = MFMA16(af[mf], bfr[nf], acc[mf][nf]);                       \
    }                                                                               \
  }

  STAGEG(sA0, sB0, 0)
  for (int t = 0; t < nt; t += 2) {
    STAGEG(sA1, sB1, t + 1)                      // prefetch odd tile (distinct bufs)
    asm volatile("s_waitcnt vmcnt(6)\n\ts_barrier" ::: "memory");  // tile t landed
    GCOMPUTE(sA0, sB0)
    asm volatile("s_barrier" ::: "memory");      // all waves done reading sA0/sB0
    if (t + 2 < nt) {
      STAGEG(sA0, sB0, t + 2)
      asm volatile("s_waitcnt vmcnt(6)\n\ts_barrier" ::: "memory");  // tile t+1 landed
    } else {
      asm volatile("s_waitcnt vmcnt(0)\n\ts_barrier" ::: "memory");  // final drain
    }
    GCOMPUTE(sA1, sB1)
    asm volatile("s_barrier" ::: "memory");      // protect sA1/sB1 restage next iter
  }
#undef STAGEG
#undef GCOMPUTE

#pragma unroll
  for (int mf = 0; mf < 4; mf++)
#pragma unroll
    for (int nf = 0; nf < 4; nf++)
#pragma unroll
      for (int r = 0; r < 4; r++) {
        int m = m0 + wr * 64 + mf * 16 + l4 * 4 + r;
        int n = n0 + wc * 64 + nf * 16 + l15;
        float v = acc[mf][nf][r];
        if constexpr (MODE == 1) {
          ((float*)C0)[(size_t)m * ldc + n] = v;
        } else if constexpr (MODE == 2) {
          ((bf16_t*)C0)[(size_t)m * 3072 + (n >> 7) * 192 + (n & 127)] = (bf16_t)v;
        } else if constexpr (MODE == 4) {
          if (n < 1280) {
            ((bf16_t*)C0)[(size_t)m * 1280 + n] = (bf16_t)v;
          } else if (n < 2304) {
            int nn = n - 1280;
            ((bf16_t*)C1)[(size_t)m * 3072 + (nn >> 6) * 192 + 128 + (nn & 63)] = (bf16_t)v;
          } else {
            int nn = n - 2304;
            ((bf16_t*)C2)[(size_t)m * 3072 + (nn >> 6) * 192 + 128 + (nn & 63)] = (bf16_t)v;
          }
        } else {  // MODE 5
          if (n < 2048) {
            ((bf16_t*)C0)[(size_t)m * 3072 + (n >> 7) * 192 + (n & 127)] = (bf16_t)v;
          } else {
            ((bf16_t*)C1)[(size_t)m * 3072 + (n - 2048)] = (bf16_t)v;
          }
        }
      }
}

// ---------------------------------------------------------------- flash attention (causal)
// 8 waves / 512 threads, pairs (c,31-c) of 128-row chunks; statically distinct
// K/V double buffers, 2x-unrolled loop, gload_lds prefetch one tile ahead.
__global__ __launch_bounds__(512, 2) void attn_kernel(const bf16_t* __restrict__ q,
                                                      const bf16_t* __restrict__ kbuf,
                                                      const bf16_t* __restrict__ vt,
                                                      bf16_t* __restrict__ ao) {
  __shared__ __align__(16) bf16_t sK0[64][192];  // perm-24 swizzle
  __shared__ __align__(16) bf16_t sK1[64][192];
  __shared__ __align__(16) bf16_t sV0[192][64];  // xor-8 chunk swizzle
  __shared__ __align__(16) bf16_t sV1[192][64];

  const int tid = threadIdx.x, l = tid & 63, w = tid >> 6;
  const int l15 = l & 15, l4 = (l >> 4) & 3;
  const int bh = blockIdx.x & 31;            // same-bh blocks share an XCD (i%8 preserved)
  const int c = blockIdx.x >> 5;             // pair index 0..7
  const int b = bh >> 4, h = bh & 15;
  const int ca = c, cb = 15 - c;             // 128-row chunks
  const int ra = ca * 128 + w * 16;
  const int rb = cb * 128 + w * 16;
  const int tga = 2 * ca + (w >> 2);         // diag k-tile for this wave's chunk-a rows
  const int tgb = 2 * cb + (w >> 2);

  const bf16_t* qp = q + (size_t)b * 2048 * 3072 + h * 192;
  const bf16_t* kp = kbuf + (size_t)b * 2048 * 3072 + h * 192;
  const bf16_t* vp = vt + (size_t)bh * 192 * 2048;

  bf16x8 qf[2][6];
#pragma unroll
  for (int kd = 0; kd < 6; kd++) {
    qf[0][kd] = *(const bf16x8*)(qp + (size_t)(ra + l15) * 3072 + kd * 32 + l4 * 8);
    qf[1][kd] = *(const bf16x8*)(qp + (size_t)(rb + l15) * 3072 + kd * 32 + l4 * 8);
  }

  f32x4 o[2][12] = {};
  float mrow[2] = {-__builtin_inff(), -__builtin_inff()};
  float lrow[2] = {0.0f, 0.0f};

  const float scale = 0.07216878364870322f;  // 1/sqrt(192)
  const float THR = 7.0f;                    // defer-max threshold
  const int nkt = 2 * cb + 2;                // always even
  const int src0 = l15 + ((l4 & 1) << 5);
  const int src1 = src0 + 16;
  const bool hibank = (l4 & 2) != 0;

#define STAGE(SK, SV, KT)                                                           \
  {                                                                                 \
    const int k0s = (KT) * 64;                                                      \
    _Pragma("unroll")                                                               \
    for (int r = 0; r < 3; r++) {                                                   \
      int i = r * 512 + tid;                                                        \
      int row = i / 24, cc = i % 24;                                                \
      int g = cc - (row & 7) * 3;                                                   \
      if (g < 0) g += 24;                                                           \
      gload_lds16(kp + (size_t)(k0s + row) * 3072 + g * 8,                          \
                  (char*)&SK[0][0] + (size_t)(r * 512 + w * 64) * 16);              \
    }                                                                               \
    _Pragma("unroll")                                                               \
    for (int r = 0; r < 3; r++) {                                                   \
      int i = r * 512 + tid;                                                        \
      int d = i >> 3, cc = i & 7;                                                   \
      gload_lds16(vp + (size_t)d * 2048 + k0s + (cc ^ (d & 7)) * 8,                 \
                  (char*)&SV[0][0] + (size_t)(r * 512 + w * 64) * 16);              \
    }                                                                               \
  }

#define SOFTMAX_CHUNK(c, rbase, tg)                                                    \
    {                                                                                  \
      const bool diag = (kt == (tg));                                                  \
      _Pragma("unroll")                                                                \
      for (int nf = 0; nf < 4; nf++)                                                   \
        _Pragma("unroll")                                                              \
        for (int r = 0; r < 4; r++) {                                                  \
          float sv = s[c][nf][r] * scale;                                              \
          if (diag) {                                                                  \
            int ktok = k0 + nf * 16 + l4 * 4 + r;                                      \
            if (ktok > (rbase) + l15) sv = -__builtin_inff();                          \
          }                                                                            \
          s[c][nf][r] = sv;                                                            \
        }                                                                              \
      float m_in = s[c][0][0];                                                         \
      _Pragma("unroll")                                                                \
      for (int nf = 0; nf < 4; nf++)                                                   \
        _Pragma("unroll")                                                              \
        for (int r = 0; r < 4; r++)                                                    \
          if (nf | r) m_in = fmaxf(m_in, s[c][nf][r]);                                 \
      m_in = fmaxf(m_in, __shfl_xor(m_in, 16));                                        \
      m_in = fmaxf(m_in, __shfl_xor(m_in, 32));                                        \
      if (!__all(m_in - mrow[c] <= THR)) {                                             \
        float mn = fmaxf(mrow[c], m_in);                                               \
        float alpha = __expf(mrow[c] - mn);                                            \
        mrow[c] = mn;                                                                  \
        lrow[c] *= alpha;                                                              \
        f32x4 av;                                                                      \
        _Pragma("unroll")                                                              \
        for (int r = 0; r < 4; r++) av[r] = __shfl(alpha, l4 * 4 + r);                 \
        _Pragma("unroll")                                                              \
        for (int nf2 = 0; nf2 < 12; nf2++) o[c][nf2] *= av;                            \
      }                                                                                \
      float rs = 0.0f;                                                                 \
      _Pragma("unroll")                                                                \
      for (int nf = 0; nf < 4; nf++)                                                   \
        _Pragma("unroll")                                                              \
        for (int r = 0; r < 4; r++) {                                                  \
          float pv = __expf(s[c][nf][r] - mrow[c]);                                    \
          s[c][nf][r] = pv;                                                            \
          rs += pv;                                                                    \
        }                                                                              \
      rs += __shfl_xor(rs, 16);                                                        \
      rs += __shfl_xor(rs, 32);                                                        \
      lrow[c] += rs;                                                                   \
      uint32_t wq[8];                                                                  \
      _Pragma("unroll")                                                                \
      for (int nf = 0; nf < 4; nf++) {                                                 \
        wq[nf * 2 + 0] = pkbf(s[c][nf][0], s[c][nf][1]);                               \
        wq[nf * 2 + 1] = pkbf(s[c][nf][2], s[c][nf][3]);                               \
      }                                                                                \
      _Pragma("unroll")                                                                \
      for (int ks = 0; ks < 2; ks++) {                                                 \
        uint32_t A0 = __shfl(wq[(2 * ks) * 2 + 0], src0);                              \
        uint32_t A1 = __shfl(wq[(2 * ks) * 2 + 1], src0);                              \
        uint32_t B0 = __shfl(wq[(2 * ks + 1) * 2 + 0], src0);                          \
        uint32_t B1 = __shfl(wq[(2 * ks + 1) * 2 + 1], src0);                          \
        uint32_t C0w = __shfl(wq[(2 * ks) * 2 + 0], src1);                             \
        uint32_t C1w = __shfl(wq[(2 * ks) * 2 + 1], src1);                             \
        uint32_t D0 = __shfl(wq[(2 * ks + 1) * 2 + 0], src1);                          \
        uint32_t D1 = __shfl(wq[(2 * ks + 1) * 2 + 1], src1);                          \
        union { uint32_t u[4]; bf16x8 v; } fr;                                         \
        fr.u[0] = hibank ? B0 : A0;                                                    \
        fr.u[1] = hibank ? B1 : A1;                                                    \
        fr.u[2] = hibank ? D0 : C0w;                                                   \
        fr.u[3] = hibank ? D1 : C1w;                                                   \
        pa[c][ks] = fr.v;                                                              \
      }                                                                                \
    }

#define TILE_BODY(SK, SV, KT)                                                          \
  {                                                                                    \
    const int kt = (KT);                                                               \
    const int k0 = kt * 64;                                                            \
    const bool act_a = (kt <= tga);                                                    \
    const bool act_b = (kt <= tgb);                                                    \
    f32x4 s[2][4] = {};                                                                \
    _Pragma("unroll")                                                                  \
    for (int kd = 0; kd < 6; kd++) {                                                   \
      bf16x8 bk[4];                                                                    \
      _Pragma("unroll")                                                                \
      for (int nf = 0; nf < 4; nf++) {                                                 \
        int row = nf * 16 + l15;                                                       \
        int cl = kd * 4 + l4 + (row & 7) * 3;                                          \
        if (cl >= 24) cl -= 24;                                                        \
        bk[nf] = *(const bf16x8*)(&SK[row][cl * 8]);                                   \
      }                                                                                \
      if (act_b) {                                                                     \
        _Pragma("unroll")                                                              \
        for (int nf = 0; nf < 4; nf++)                                                 \
          s[1][nf] = MFMA16(bk[nf], qf[1][kd], s[1][nf]);                              \
      }                                                                                \
      if (act_a) {                                                                     \
        _Pragma("unroll")                                                              \
        for (int nf = 0; nf < 4; nf++)                                                 \
          s[0][nf] = MFMA16(bk[nf], qf[0][kd], s[0][nf]);                              \
      }                                                                                \
    }                                                                                  \
    bf16x8 pa[2][2] = {};                                                              \
    if (act_b) SOFTMAX_CHUNK(1, rb, tgb)                                               \
    if (act_a) SOFTMAX_CHUNK(0, ra, tga)                                               \
    _Pragma("unroll")                                                                  \
    for (int ks = 0; ks < 2; ks++) {                                                   \
      _Pragma("unroll")                                                                \
      for (int nf2 = 0; nf2 < 12; nf2++) {                                             \
        int d = nf2 * 16 + l15;                                                        \
        int cl = (ks * 4 + l4) ^ (d & 7);                                              \
        bf16x8 vb = *(const bf16x8*)(&SV[d][cl * 8]);                                  \
        if (act_b) o[1][nf2] = MFMA16(pa[1][ks], vb, o[1][nf2]);                       \
        if (act_a) o[0][nf2] = MFMA16(pa[0][ks], vb, o[0][nf2]);                       \
      }                                                                                \
    }                                                                                  \
  }

  STAGE(sK0, sV0, 0)
  __syncthreads();  // tile 0 ready

  for (int kt0 = 0; kt0 < nkt; kt0 += 2) {
    STAGE(sK1, sV1, kt0 + 1)
    TILE_BODY(sK0, sV0, kt0)
    __syncthreads();
    if (kt0 + 2 < nkt) STAGE(sK0, sV0, kt0 + 2)
    TILE_BODY(sK1, sV1, kt0 + 1)
    __syncthreads();
  }
#undef STAGE
#undef SOFTMAX_CHUNK
#undef TILE_BODY

  // epilogue: O/l -> ao (b*T+q, h*192+d), both chunks; l lives at lane l15=q
#pragma unroll
  for (int mf = 0; mf < 2; mf++) {
    const int rbase = (mf == 0) ? ra : rb;
#pragma unroll
    for (int r = 0; r < 4; r++) {
      float lv = __shfl(lrow[mf], l4 * 4 + r);
      float inv = 1.0f / lv;
      int qrow = rbase + l4 * 4 + r;
#pragma unroll
      for (int nf2 = 0; nf2 < 12; nf2++) {
        int d = nf2 * 16 + l15;
        ao[(size_t)(b * 2048 + qrow) * 3072 + h * 192 + d] = (bf16_t)(o[mf][nf2][r] * inv);
      }
    }
  }
}

// ----------------------------------------------------------------
extern "C" void kernel_launch(void* const* d_in, const int* in_sizes, int n_in,
                              void* d_out, int out_size, void* d_ws, size_t ws_size,
                              hipStream_t stream) {
  const float* x       = (const float*)d_in[0];
  const float* wq_down = (const float*)d_in[1];
  const float* wq_up   = (const float*)d_in[2];
  const float* wq_rope = (const float*)d_in[3];
  const float* wkv_down= (const float*)d_in[4];
  const float* wk_up   = (const float*)d_in[5];
  const float* wv_up   = (const float*)d_in[6];
  const float* wk_rope = (const float*)d_in[7];
  const float* wo      = (const float*)d_in[8];
  float* out = (float*)d_out;

  char* p = (char*)d_ws;
  auto take = [&](size_t elems) { bf16_t* r = (bf16_t*)p; p += elems * 2; return r; };
  bf16_t* xb    = take(4096ull * 2048);
  bf16_t* fw1   = take(3328ull * 2048);  // [wq_down(768) | wkv_down(512) | wq_rope(1024) | wk_rope(1024)]^T
  bf16_t* wqu_t = take(2048ull * 768);
  bf16_t* fw2   = take(5120ull * 512);   // [wk_up(2048) | wv_up(3072)]^T
  bf16_t* wo_t  = take(2048ull * 3072);
  bf16_t* qkvd  = take(4096ull * 1280);  // [q_down(768) | latent(512)]
  bf16_t* qbuf  = take(4096ull * 3072);
  bf16_t* kbuf  = take(4096ull * 3072);
  bf16_t* vbuf  = take(4096ull * 3072);
  bf16_t* vt    = take(4096ull * 3072);
  bf16_t* ao    = vbuf;  // v row-major dead after transpose_v; reuse for attention out

  dim3 tb(32, 8);
  cvt_f32_to_bf16<<<8192, 256, 0, stream>>>(x, xb);
  transpose_w<<<dim3(24, 64), tb, 0, stream>>>(wq_down,  fw1,                 2048, 768);
  transpose_w<<<dim3(16, 64), tb, 0, stream>>>(wkv_down, fw1 + 768ull * 2048, 2048, 512);
  transpose_w<<<dim3(32, 64), tb, 0, stream>>>(wq_rope,  fw1 + 1280ull * 2048,2048, 1024);
  transpose_w<<<dim3(32, 64), tb, 0, stream>>>(wk_rope,  fw1 + 2304ull * 2048,2048, 1024);
  transpose_w<<<dim3(64, 24), tb, 0, stream>>>(wq_up,    wqu_t,               768, 2048);
  transpose_w<<<dim3(64, 16), tb, 0, stream>>>(wk_up,    fw2,                 512, 2048);
  transpose_w<<<dim3(96, 16), tb, 0, stream>>>(wv_up,    fw2 + 2048ull * 512, 512, 3072);
  transpose_w<<<dim3(64, 96), tb, 0, stream>>>(wo,       wo_t,                3072, 2048);

  gemm_bt2<4><<<dim3(26, 16), 512, 0, stream>>>(xb, 2048, fw1, qkvd, qbuf, kbuf, 2048, 0);
  gemm_bt2<2><<<dim3(16, 16), 512, 0, stream>>>(qkvd, 1280, wqu_t, qbuf, nullptr, nullptr, 768, 0);
  gemm_bt2<5><<<dim3(40, 16), 512, 0, stream>>>(qkvd + 768, 1280, fw2, kbuf, vbuf, nullptr, 512, 0);

  rope_inplace<<<8192, 256, 0, stream>>>(qbuf);
  rope_inplace<<<8192, 256, 0, stream>>>(kbuf);
  transpose_v_kernel<<<dim3(64, 6, 32), tb, 0, stream>>>(vbuf, vt);

  attn_kernel<<<256, 512, 0, stream>>>(qbuf, kbuf, vt, ao);

  gemm_bt2<1><<<dim3(16, 16), 512, 0, stream>>>(ao, 3072, wo_t, out, nullptr, nullptr, 3072, 2048);
}

// Round 9
// 347.100 us; speedup vs baseline: 1.2184x; 1.0756x over previous
//
#include <hip/hip_runtime.h>
#include <hip/hip_bf16.h>
#include <cstdint>
#include <cstddef>

typedef __bf16 bf16_t;
typedef __bf16 bf16x8 __attribute__((ext_vector_type(8)));
typedef float f32x4 __attribute__((ext_vector_type(4)));

#define MFMA16(a, b, c) __builtin_amdgcn_mfma_f32_16x16x32_bf16((a), (b), (c), 0, 0, 0)

__device__ __forceinline__ void gload_lds16(const void* g, void* l) {
  __builtin_amdgcn_global_load_lds((__attribute__((address_space(1))) void*)(g),
                                   (__attribute__((address_space(3))) void*)(l),
                                   16, 0, 0);
}

__device__ __forceinline__ uint32_t pkbf(float lo, float hi) {
  union { bf16_t h[2]; uint32_t u; } u2;
  u2.h[0] = (bf16_t)lo; u2.h[1] = (bf16_t)hi;
  return u2.u;
}

// ---------------------------------------------------------------- cvt x fp32->bf16
__global__ __launch_bounds__(256) void cvt_f32_to_bf16(const float* __restrict__ in,
                                                       bf16_t* __restrict__ out) {
  size_t i = ((size_t)blockIdx.x * 256 + threadIdx.x) * 4;
  float4 v = *(const float4*)(in + i);
  bf16_t o[4] = {(bf16_t)v.x, (bf16_t)v.y, (bf16_t)v.z, (bf16_t)v.w};
  *(uint2*)(out + i) = *(uint2*)o;
}

// ---------------------------------------------------------------- all 8 weight transposes, one dispatch
// fp32 (R,C) -> bf16 (C,R); block routed by prefix ranges (block-uniform branches).
__global__ __launch_bounds__(256) void transpose_all(
    const float* __restrict__ s0, const float* __restrict__ s1,
    const float* __restrict__ s2, const float* __restrict__ s3,
    const float* __restrict__ s4, const float* __restrict__ s5,
    const float* __restrict__ s6, const float* __restrict__ s7,
    bf16_t* __restrict__ t0, bf16_t* __restrict__ t1, bf16_t* __restrict__ t2,
    bf16_t* __restrict__ t3, bf16_t* __restrict__ t4, bf16_t* __restrict__ t5,
    bf16_t* __restrict__ t6, bf16_t* __restrict__ t7) {
  __shared__ bf16_t tile[32][33];
  const int lid = blockIdx.x;
  const float* src; bf16_t* dst; int R, C, bx, by;
  if (lid < 1536)       { src=s0; dst=t0; R=2048; C=768;  int lo=lid;        bx=lo%24; by=lo/24; }
  else if (lid < 2560)  { src=s1; dst=t1; R=2048; C=512;  int lo=lid-1536;   bx=lo%16; by=lo/16; }
  else if (lid < 4608)  { src=s2; dst=t2; R=2048; C=1024; int lo=lid-2560;   bx=lo%32; by=lo/32; }
  else if (lid < 6656)  { src=s3; dst=t3; R=2048; C=1024; int lo=lid-4608;   bx=lo%32; by=lo/32; }
  else if (lid < 8192)  { src=s4; dst=t4; R=768;  C=2048; int lo=lid-6656;   bx=lo%64; by=lo/64; }
  else if (lid < 9216)  { src=s5; dst=t5; R=512;  C=2048; int lo=lid-8192;   bx=lo%64; by=lo/64; }
  else if (lid < 10752) { src=s6; dst=t6; R=512;  C=3072; int lo=lid-9216;   bx=lo%96; by=lo/96; }
  else                  { src=s7; dst=t7; R=3072; C=2048; int lo=lid-10752;  bx=lo%64; by=lo/64; }
  const int c0 = bx * 32, r0 = by * 32;
  const int tx = threadIdx.x, ty = threadIdx.y;
#pragma unroll
  for (int s = 0; s < 4; s++) {
    int r = ty + s * 8;
    tile[r][tx] = (bf16_t)src[(size_t)(r0 + r) * C + c0 + tx];
  }
  __syncthreads();
#pragma unroll
  for (int s = 0; s < 4; s++) {
    int r = ty + s * 8;
    dst[(size_t)(c0 + r) * R + r0 + tx] = tile[tx][r];
  }
}

// ---------------------------------------------------------------- rope in-place on both packed (4096,3072) buffers
__global__ __launch_bounds__(256) void rope_both(bf16_t* __restrict__ qb,
                                                 bf16_t* __restrict__ kb) {
  const int gid = blockIdx.x;
  bf16_t* buf = (gid < 8192) ? qb : kb;
  int idx = (gid & 8191) * 256 + threadIdx.x;
  int j = idx & 31;
  int h = (idx >> 5) & 15;
  int row = idx >> 9;           // 0..4095
  int t = row & 2047;
  size_t base = (size_t)row * 3072 + h * 192 + 128;
  float inv = expf(-(float)j * 0.28782313662425574f);
  float ang = (float)t * inv;
  float c, s;
  sincosf(ang, &s, &c);
  float x1 = (float)buf[base + j];
  float x2 = (float)buf[base + j + 32];
  buf[base + j]      = (bf16_t)(x1 * c - x2 * s);
  buf[base + j + 32] = (bf16_t)(x1 * s + x2 * c);
}

// ---------------------------------------------------------------- GEMM: C = A(M,lda)[:, :K] * Bt(N,K)^T
// 256(M)x128(N) tile, BK=64, 512 thr / 8 waves, per-wave 64x64. Double-buffered
// staging one K-step ahead, counted vmcnt(6) + raw s_barrier. K/64 even.
// MODE 1: f32 out. MODE 2: bf16 head-split CD. MODE 4: fuse1 router.
// MODE 5: n<2048 -> head-split CD to C0; n>=2048 -> v_up written DIRECTLY to vt (b,h,d,t).
template <int MODE>
__global__ __launch_bounds__(512, 2) void gemm_bt2(const bf16_t* __restrict__ A, int lda,
                                                   const bf16_t* __restrict__ Bt,
                                                   void* __restrict__ C0, void* __restrict__ C1,
                                                   void* __restrict__ C2, int K, int ldc) {
  __shared__ __align__(16) bf16_t sA0[256 * 64];
  __shared__ __align__(16) bf16_t sB0[128 * 64];
  __shared__ __align__(16) bf16_t sA1[256 * 64];
  __shared__ __align__(16) bf16_t sB1[128 * 64];
  const int tid = threadIdx.x;
  const int l = tid & 63, w = tid >> 6;
  const int l15 = l & 15, l4 = (l >> 4) & 3;
  const int wr = w >> 1, wc = w & 1;
  const int m0 = blockIdx.y * 256, n0 = blockIdx.x * 128;
  const int nt = K >> 6;

  f32x4 acc[4][4] = {};

#define STAGEG(SA, SB, KT)                                                          \
  {                                                                                 \
    const int kts = (KT) * 64;                                                      \
    _Pragma("unroll")                                                               \
    for (int r = 0; r < 4; r++) {                                                   \
      int i = r * 512 + tid;                                                        \
      int row = i >> 3, cl = i & 7;                                                 \
      int cg = cl ^ (row & 7);                                                      \
      gload_lds16(A + (size_t)(m0 + row) * lda + kts + cg * 8,                      \
                  (char*)(SA) + (size_t)(r * 512 + w * 64) * 16);                   \
    }                                                                               \
    _Pragma("unroll")                                                               \
    for (int r = 0; r < 2; r++) {                                                   \
      int i = r * 512 + tid;                                                        \
      int row = i >> 3, cl = i & 7;                                                 \
      int cg = cl ^ (row & 7);                                                      \
      gload_lds16(Bt + (size_t)(n0 + row) * K + kts + cg * 8,                       \
                  (char*)(SB) + (size_t)(r * 512 + w * 64) * 16);                   \
    }                                                                               \
  }

#define GCOMPUTE(SA, SB)                                                            \
  {                                                                                 \
    _Pragma("unroll")                                                               \
    for (int ks = 0; ks < 2; ks++) {                                                \
      bf16x8 af[4], bfr[4];                                                         \
      _Pragma("unroll")                                                             \
      for (int mf = 0; mf < 4; mf++) {                                              \
        int row = wr * 64 + mf * 16 + l15;                                          \
        int cl = (ks * 4 + l4) ^ (row & 7);                                         \
        af[mf] = *(const bf16x8*)((SA) + row * 64 + cl * 8);                        \
      }                                                                             \
      _Pragma("unroll")                                                             \
      for (int nf = 0; nf < 4; nf++) {                                              \
        int row = wc * 64 + nf * 16 + l15;                                          \
        int cl = (ks * 4 + l4) ^ (row & 7);                                         \
        bfr[nf] = *(const bf16x8*)((SB) + row * 64 + cl * 8);                       \
      }                                                                             \
      _Pragma("unroll")                                                             \
      for (int mf = 0; mf < 4; mf++)                                                \
        _Pragma("unroll")                                                           \
        for (int nf = 0; nf < 4; nf++)                                              \
          acc[mf][nf] = MFMA16(af[mf], bfr[nf], acc[mf][nf]);                       \
    }                                                                               \
  }

  STAGEG(sA0, sB0, 0)
  for (int t = 0; t < nt; t += 2) {
    STAGEG(sA1, sB1, t + 1)
    asm volatile("s_waitcnt vmcnt(6)\n\ts_barrier" ::: "memory");
    GCOMPUTE(sA0, sB0)
    asm volatile("s_barrier" ::: "memory");
    if (t + 2 < nt) {
      STAGEG(sA0, sB0, t + 2)
      asm volatile("s_waitcnt vmcnt(6)\n\ts_barrier" ::: "memory");
    } else {
      asm volatile("s_waitcnt vmcnt(0)\n\ts_barrier" ::: "memory");
    }
    GCOMPUTE(sA1, sB1)
    asm volatile("s_barrier" ::: "memory");
  }
#undef STAGEG
#undef GCOMPUTE

#pragma unroll
  for (int mf = 0; mf < 4; mf++)
#pragma unroll
    for (int nf = 0; nf < 4; nf++) {
      const int mbase = m0 + wr * 64 + mf * 16 + l4 * 4;
      const int n = n0 + wc * 64 + nf * 16 + l15;
      if constexpr (MODE == 1) {
#pragma unroll
        for (int r = 0; r < 4; r++)
          ((float*)C0)[(size_t)(mbase + r) * ldc + n] = acc[mf][nf][r];
      } else if constexpr (MODE == 2) {
#pragma unroll
        for (int r = 0; r < 4; r++)
          ((bf16_t*)C0)[(size_t)(mbase + r) * 3072 + (n >> 7) * 192 + (n & 127)] =
              (bf16_t)acc[mf][nf][r];
      } else if constexpr (MODE == 4) {
        if (n < 1280) {
#pragma unroll
          for (int r = 0; r < 4; r++)
            ((bf16_t*)C0)[(size_t)(mbase + r) * 1280 + n] = (bf16_t)acc[mf][nf][r];
        } else if (n < 2304) {
          int nn = n - 1280;
#pragma unroll
          for (int r = 0; r < 4; r++)
            ((bf16_t*)C1)[(size_t)(mbase + r) * 3072 + (nn >> 6) * 192 + 128 + (nn & 63)] =
                (bf16_t)acc[mf][nf][r];
        } else {
          int nn = n - 2304;
#pragma unroll
          for (int r = 0; r < 4; r++)
            ((bf16_t*)C2)[(size_t)(mbase + r) * 3072 + (nn >> 6) * 192 + 128 + (nn & 63)] =
                (bf16_t)acc[mf][nf][r];
        }
      } else {  // MODE 5
        if (n < 2048) {
#pragma unroll
          for (int r = 0; r < 4; r++)
            ((bf16_t*)C0)[(size_t)(mbase + r) * 3072 + (n >> 7) * 192 + (n & 127)] =
                (bf16_t)acc[mf][nf][r];
        } else {
          // v_up -> vt (b, h, d, t) directly; 4 r-values are 4 consecutive t
          int nn = n - 2048;            // 0..3071
          int hh = nn / 192, dd = nn - hh * 192;
          int bb = mbase >> 11, tt = mbase & 2047;
          bf16_t pk4[4] = {(bf16_t)acc[mf][nf][0], (bf16_t)acc[mf][nf][1],
                           (bf16_t)acc[mf][nf][2], (bf16_t)acc[mf][nf][3]};
          *(uint2*)((bf16_t*)C1 + ((size_t)(bb * 16 + hh) * 192 + dd) * 2048 + tt) =
              *(uint2*)pk4;
        }
      }
    }
}

// ---------------------------------------------------------------- flash attention (causal)
// 8 waves / 512 threads, pairs (c,31-c) of 128-row chunks; statically distinct
// K/V double buffers, 2x-unrolled loop, gload_lds prefetch one tile ahead.
__global__ __launch_bounds__(512, 2) void attn_kernel(const bf16_t* __restrict__ q,
                                                      const bf16_t* __restrict__ kbuf,
                                                      const bf16_t* __restrict__ vt,
                                                      bf16_t* __restrict__ ao) {
  __shared__ __align__(16) bf16_t sK0[64][192];  // perm-24 swizzle
  __shared__ __align__(16) bf16_t sK1[64][192];
  __shared__ __align__(16) bf16_t sV0[192][64];  // xor-8 chunk swizzle
  __shared__ __align__(16) bf16_t sV1[192][64];

  const int tid = threadIdx.x, l = tid & 63, w = tid >> 6;
  const int l15 = l & 15, l4 = (l >> 4) & 3;
  const int bh = blockIdx.x & 31;            // same-bh blocks share an XCD (i%8 preserved)
  const int c = blockIdx.x >> 5;             // pair index 0..7
  const int b = bh >> 4, h = bh & 15;
  const int ca = c, cb = 15 - c;             // 128-row chunks
  const int ra = ca * 128 + w * 16;
  const int rb = cb * 128 + w * 16;
  const int tga = 2 * ca + (w >> 2);         // diag k-tile for this wave's chunk-a rows
  const int tgb = 2 * cb + (w >> 2);

  const bf16_t* qp = q + (size_t)b * 2048 * 3072 + h * 192;
  const bf16_t* kp = kbuf + (size_t)b * 2048 * 3072 + h * 192;
  const bf16_t* vp = vt + (size_t)bh * 192 * 2048;

  bf16x8 qf[2][6];
#pragma unroll
  for (int kd = 0; kd < 6; kd++) {
    qf[0][kd] = *(const bf16x8*)(qp + (size_t)(ra + l15) * 3072 + kd * 32 + l4 * 8);
    qf[1][kd] = *(const bf16x8*)(qp + (size_t)(rb + l15) * 3072 + kd * 32 + l4 * 8);
  }

  f32x4 o[2][12] = {};
  float mrow[2] = {-__builtin_inff(), -__builtin_inff()};
  float lrow[2] = {0.0f, 0.0f};

  const float scale = 0.07216878364870322f;  // 1/sqrt(192)
  const float THR = 7.0f;                    // defer-max threshold
  const int nkt = 2 * cb + 2;                // always even
  const int src0 = l15 + ((l4 & 1) << 5);
  const int src1 = src0 + 16;
  const bool hibank = (l4 & 2) != 0;

#define STAGE(SK, SV, KT)                                                           \
  {                                                                                 \
    const int k0s = (KT) * 64;                                                      \
    _Pragma("unroll")                                                               \
    for (int r = 0; r < 3; r++) {                                                   \
      int i = r * 512 + tid;                                                        \
      int row = i / 24, cc = i % 24;                                                \
      int g = cc - (row & 7) * 3;                                                   \
      if (g < 0) g += 24;                                                           \
      gload_lds16(kp + (size_t)(k0s + row) * 3072 + g * 8,                          \
                  (char*)&SK[0][0] + (size_t)(r * 512 + w * 64) * 16);              \
    }                                                                               \
    _Pragma("unroll")                                                               \
    for (int r = 0; r < 3; r++) {                                                   \
      int i = r * 512 + tid;                                                        \
      int d = i >> 3, cc = i & 7;                                                   \
      gload_lds16(vp + (size_t)d * 2048 + k0s + (cc ^ (d & 7)) * 8,                 \
                  (char*)&SV[0][0] + (size_t)(r * 512 + w * 64) * 16);              \
    }                                                                               \
  }

#define SOFTMAX_CHUNK(c, rbase, tg)                                                    \
    {                                                                                  \
      const bool diag = (kt == (tg));                                                  \
      _Pragma("unroll")                                                                \
      for (int nf = 0; nf < 4; nf++)                                                   \
        _Pragma("unroll")                                                              \
        for (int r = 0; r < 4; r++) {                                                  \
          float sv = s[c][nf][r] * scale;                                              \
          if (diag) {                                                                  \
            int ktok = k0 + nf * 16 + l4 * 4 + r;                                      \
            if (ktok > (rbase) + l15) sv = -__builtin_inff();                          \
          }                                                                            \
          s[c][nf][r] = sv;                                                            \
        }                                                                              \
      float m_in = s[c][0][0];                                                         \
      _Pragma("unroll")                                                                \
      for (int nf = 0; nf < 4; nf++)                                                   \
        _Pragma("unroll")                                                              \
        for (int r = 0; r < 4; r++)                                                    \
          if (nf | r) m_in = fmaxf(m_in, s[c][nf][r]);                                 \
      m_in = fmaxf(m_in, __shfl_xor(m_in, 16));                                        \
      m_in = fmaxf(m_in, __shfl_xor(m_in, 32));                                        \
      if (!__all(m_in - mrow[c] <= THR)) {                                             \
        float mn = fmaxf(mrow[c], m_in);                                               \
        float alpha = __expf(mrow[c] - mn);                                            \
        mrow[c] = mn;                                                                  \
        lrow[c] *= alpha;                                                              \
        f32x4 av;                                                                      \
        _Pragma("unroll")                                                              \
        for (int r = 0; r < 4; r++) av[r] = __shfl(alpha, l4 * 4 + r);                 \
        _Pragma("unroll")                                                              \
        for (int nf2 = 0; nf2 < 12; nf2++) o[c][nf2] *= av;                            \
      }                                                                                \
      float rs = 0.0f;                                                                 \
      _Pragma("unroll")                                                                \
      for (int nf = 0; nf < 4; nf++)                                                   \
        _Pragma("unroll")                                                              \
        for (int r = 0; r < 4; r++) {                                                  \
          float pv = __expf(s[c][nf][r] - mrow[c]);                                    \
          s[c][nf][r] = pv;                                                            \
          rs += pv;                                                                    \
        }                                                                              \
      rs += __shfl_xor(rs, 16);                                                        \
      rs += __shfl_xor(rs, 32);                                                        \
      lrow[c] += rs;                                                                   \
      uint32_t wq[8];                                                                  \
      _Pragma("unroll")                                                                \
      for (int nf = 0; nf < 4; nf++) {                                                 \
        wq[nf * 2 + 0] = pkbf(s[c][nf][0], s[c][nf][1]);                               \
        wq[nf * 2 + 1] = pkbf(s[c][nf][2], s[c][nf][3]);                               \
      }                                                                                \
      _Pragma("unroll")                                                                \
      for (int ks = 0; ks < 2; ks++) {                                                 \
        uint32_t A0 = __shfl(wq[(2 * ks) * 2 + 0], src0);                              \
        uint32_t A1 = __shfl(wq[(2 * ks) * 2 + 1], src0);                              \
        uint32_t B0 = __shfl(wq[(2 * ks + 1) * 2 + 0], src0);                          \
        uint32_t B1 = __shfl(wq[(2 * ks + 1) * 2 + 1], src0);                          \
        uint32_t C0w = __shfl(wq[(2 * ks) * 2 + 0], src1);                             \
        uint32_t C1w = __shfl(wq[(2 * ks) * 2 + 1], src1);                             \
        uint32_t D0 = __shfl(wq[(2 * ks + 1) * 2 + 0], src1);                          \
        uint32_t D1 = __shfl(wq[(2 * ks + 1) * 2 + 1], src1);                          \
        union { uint32_t u[4]; bf16x8 v; } fr;                                         \
        fr.u[0] = hibank ? B0 : A0;                                                    \
        fr.u[1] = hibank ? B1 : A1;                                                    \
        fr.u[2] = hibank ? D0 : C0w;                                                   \
        fr.u[3] = hibank ? D1 : C1w;                                                   \
        pa[c][ks] = fr.v;                                                              \
      }                                                                                \
    }

#define TILE_BODY(SK, SV, KT)                                                          \
  {                                                                                    \
    const int kt = (KT);                                                               \
    const int k0 = kt * 64;                                                            \
    const bool act_a = (kt <= tga);                                                    \
    const bool act_b = (kt <= tgb);                                                    \
    f32x4 s[2][4] = {};                                                                \
    _Pragma("unroll")                                                                  \
    for (int kd = 0; kd < 6; kd++) {                                                   \
      bf16x8 bk[4];                                                                    \
      _Pragma("unroll")                                                                \
      for (int nf = 0; nf < 4; nf++) {                                                 \
        int row = nf * 16 + l15;                                                       \
        int cl = kd * 4 + l4 + (row & 7) * 3;                                          \
        if (cl >= 24) cl -= 24;                                                        \
        bk[nf] = *(const bf16x8*)(&SK[row][cl * 8]);                                   \
      }                                                                                \
      if (act_b) {                                                                     \
        _Pragma("unroll")                                                              \
        for (int nf = 0; nf < 4; nf++)                                                 \
          s[1][nf] = MFMA16(bk[nf], qf[1][kd], s[1][nf]);                              \
      }                                                                                \
      if (act_a) {                                                                     \
        _Pragma("unroll")                                                              \
        for (int nf = 0; nf < 4; nf++)                                                 \
          s[0][nf] = MFMA16(bk[nf], qf[0][kd], s[0][nf]);                              \
      }                                                                                \
    }                                                                                  \
    bf16x8 pa[2][2] = {};                                                              \
    if (act_b) SOFTMAX_CHUNK(1, rb, tgb)                                               \
    if (act_a) SOFTMAX_CHUNK(0, ra, tga)                                               \
    _Pragma("unroll")                                                                  \
    for (int ks = 0; ks < 2; ks++) {                                                   \
      _Pragma("unroll")                                                                \
      for (int nf2 = 0; nf2 < 12; nf2++) {                                             \
        int d = nf2 * 16 + l15;                                                        \
        int cl = (ks * 4 + l4) ^ (d & 7);                                              \
        bf16x8 vb = *(const bf16x8*)(&SV[d][cl * 8]);                                  \
        if (act_b) o[1][nf2] = MFMA16(pa[1][ks], vb, o[1][nf2]);                       \
        if (act_a) o[0][nf2] = MFMA16(pa[0][ks], vb, o[0][nf2]);                       \
      }                                                                                \
    }                                                                                  \
  }

  STAGE(sK0, sV0, 0)
  __syncthreads();  // tile 0 ready

  for (int kt0 = 0; kt0 < nkt; kt0 += 2) {
    STAGE(sK1, sV1, kt0 + 1)
    TILE_BODY(sK0, sV0, kt0)
    __syncthreads();
    if (kt0 + 2 < nkt) STAGE(sK0, sV0, kt0 + 2)
    TILE_BODY(sK1, sV1, kt0 + 1)
    __syncthreads();
  }
#undef STAGE
#undef SOFTMAX_CHUNK
#undef TILE_BODY

  // epilogue: O/l -> ao (b*T+q, h*192+d), both chunks; l lives at lane l15=q
#pragma unroll
  for (int mf = 0; mf < 2; mf++) {
    const int rbase = (mf == 0) ? ra : rb;
#pragma unroll
    for (int r = 0; r < 4; r++) {
      float lv = __shfl(lrow[mf], l4 * 4 + r);
      float inv = 1.0f / lv;
      int qrow = rbase + l4 * 4 + r;
#pragma unroll
      for (int nf2 = 0; nf2 < 12; nf2++) {
        int d = nf2 * 16 + l15;
        ao[(size_t)(b * 2048 + qrow) * 3072 + h * 192 + d] = (bf16_t)(o[mf][nf2][r] * inv);
      }
    }
  }
}

// ----------------------------------------------------------------
extern "C" void kernel_launch(void* const* d_in, const int* in_sizes, int n_in,
                              void* d_out, int out_size, void* d_ws, size_t ws_size,
                              hipStream_t stream) {
  const float* x       = (const float*)d_in[0];
  const float* wq_down = (const float*)d_in[1];
  const float* wq_up   = (const float*)d_in[2];
  const float* wq_rope = (const float*)d_in[3];
  const float* wkv_down= (const float*)d_in[4];
  const float* wk_up   = (const float*)d_in[5];
  const float* wv_up   = (const float*)d_in[6];
  const float* wk_rope = (const float*)d_in[7];
  const float* wo      = (const float*)d_in[8];
  float* out = (float*)d_out;

  char* p = (char*)d_ws;
  auto take = [&](size_t elems) { bf16_t* r = (bf16_t*)p; p += elems * 2; return r; };
  bf16_t* xb    = take(4096ull * 2048);
  bf16_t* fw1   = take(3328ull * 2048);  // [wq_down(768) | wkv_down(512) | wq_rope(1024) | wk_rope(1024)]^T
  bf16_t* wqu_t = take(2048ull * 768);
  bf16_t* fw2   = take(5120ull * 512);   // [wk_up(2048) | wv_up(3072)]^T
  bf16_t* wo_t  = take(2048ull * 3072);
  bf16_t* qkvd  = take(4096ull * 1280);  // [q_down(768) | latent(512)]
  bf16_t* qbuf  = take(4096ull * 3072);
  bf16_t* kbuf  = take(4096ull * 3072);
  bf16_t* ao    = take(4096ull * 3072);
  bf16_t* vt    = take(4096ull * 3072);

  dim3 tb(32, 8);
  cvt_f32_to_bf16<<<8192, 256, 0, stream>>>(x, xb);
  transpose_all<<<16896, tb, 0, stream>>>(
      wq_down, wkv_down, wq_rope, wk_rope, wq_up, wk_up, wv_up, wo,
      fw1, fw1 + 768ull * 2048, fw1 + 1280ull * 2048, fw1 + 2304ull * 2048,
      wqu_t, fw2, fw2 + 2048ull * 512, wo_t);

  gemm_bt2<4><<<dim3(26, 16), 512, 0, stream>>>(xb, 2048, fw1, qkvd, qbuf, kbuf, 2048, 0);
  gemm_bt2<2><<<dim3(16, 16), 512, 0, stream>>>(qkvd, 1280, wqu_t, qbuf, nullptr, nullptr, 768, 0);
  gemm_bt2<5><<<dim3(40, 16), 512, 0, stream>>>(qkvd + 768, 1280, fw2, kbuf, vt, nullptr, 512, 0);

  rope_both<<<16384, 256, 0, stream>>>(qbuf, kbuf);

  attn_kernel<<<256, 512, 0, stream>>>(qbuf, kbuf, vt, ao);

  gemm_bt2<1><<<dim3(16, 16), 512, 0, stream>>>(ao, 3072, wo_t, out, nullptr, nullptr, 3072, 2048);
}

// Round 10
// 341.339 us; speedup vs baseline: 1.2389x; 1.0169x over previous
//
#include <hip/hip_runtime.h>
#include <hip/hip_bf16.h>
#include <cstdint>
#include <cstddef>

typedef __bf16 bf16_t;
typedef __bf16 bf16x8 __attribute__((ext_vector_type(8)));
typedef float f32x4 __attribute__((ext_vector_type(4)));

#define MFMA16(a, b, c) __builtin_amdgcn_mfma_f32_16x16x32_bf16((a), (b), (c), 0, 0, 0)

__device__ __forceinline__ void gload_lds16(const void* g, void* l) {
  __builtin_amdgcn_global_load_lds((__attribute__((address_space(1))) void*)(g),
                                   (__attribute__((address_space(3))) void*)(l),
                                   16, 0, 0);
}

__device__ __forceinline__ uint32_t pkbf(float lo, float hi) {
  union { bf16_t h[2]; uint32_t u; } u2;
  u2.h[0] = (bf16_t)lo; u2.h[1] = (bf16_t)hi;
  return u2.u;
}

// ---------------------------------------------------------------- cvt x fp32->bf16
__global__ __launch_bounds__(256) void cvt_f32_to_bf16(const float* __restrict__ in,
                                                       bf16_t* __restrict__ out) {
  size_t i = ((size_t)blockIdx.x * 256 + threadIdx.x) * 4;
  float4 v = *(const float4*)(in + i);
  bf16_t o[4] = {(bf16_t)v.x, (bf16_t)v.y, (bf16_t)v.z, (bf16_t)v.w};
  *(uint2*)(out + i) = *(uint2*)o;
}

// ---------------------------------------------------------------- all 8 weight transposes, one dispatch
__global__ __launch_bounds__(256) void transpose_all(
    const float* __restrict__ s0, const float* __restrict__ s1,
    const float* __restrict__ s2, const float* __restrict__ s3,
    const float* __restrict__ s4, const float* __restrict__ s5,
    const float* __restrict__ s6, const float* __restrict__ s7,
    bf16_t* __restrict__ t0, bf16_t* __restrict__ t1, bf16_t* __restrict__ t2,
    bf16_t* __restrict__ t3, bf16_t* __restrict__ t4, bf16_t* __restrict__ t5,
    bf16_t* __restrict__ t6, bf16_t* __restrict__ t7) {
  __shared__ bf16_t tile[32][33];
  const int lid = blockIdx.x;
  const float* src; bf16_t* dst; int R, C, bx, by;
  if (lid < 1536)       { src=s0; dst=t0; R=2048; C=768;  int lo=lid;        bx=lo%24; by=lo/24; }
  else if (lid < 2560)  { src=s1; dst=t1; R=2048; C=512;  int lo=lid-1536;   bx=lo%16; by=lo/16; }
  else if (lid < 4608)  { src=s2; dst=t2; R=2048; C=1024; int lo=lid-2560;   bx=lo%32; by=lo/32; }
  else if (lid < 6656)  { src=s3; dst=t3; R=2048; C=1024; int lo=lid-4608;   bx=lo%32; by=lo/32; }
  else if (lid < 8192)  { src=s4; dst=t4; R=768;  C=2048; int lo=lid-6656;   bx=lo%64; by=lo/64; }
  else if (lid < 9216)  { src=s5; dst=t5; R=512;  C=2048; int lo=lid-8192;   bx=lo%64; by=lo/64; }
  else if (lid < 10752) { src=s6; dst=t6; R=512;  C=3072; int lo=lid-9216;   bx=lo%96; by=lo/96; }
  else                  { src=s7; dst=t7; R=3072; C=2048; int lo=lid-10752;  bx=lo%64; by=lo/64; }
  const int c0 = bx * 32, r0 = by * 32;
  const int tx = threadIdx.x, ty = threadIdx.y;
#pragma unroll
  for (int s = 0; s < 4; s++) {
    int r = ty + s * 8;
    tile[r][tx] = (bf16_t)src[(size_t)(r0 + r) * C + c0 + tx];
  }
  __syncthreads();
#pragma unroll
  for (int s = 0; s < 4; s++) {
    int r = ty + s * 8;
    dst[(size_t)(c0 + r) * R + r0 + tx] = tile[tx][r];
  }
}

// ---------------------------------------------------------------- rope in-place on both packed (4096,3072) buffers
__global__ __launch_bounds__(256) void rope_both(bf16_t* __restrict__ qb,
                                                 bf16_t* __restrict__ kb) {
  const int gid = blockIdx.x;
  bf16_t* buf = (gid < 8192) ? qb : kb;
  int idx = (gid & 8191) * 256 + threadIdx.x;
  int j = idx & 31;
  int h = (idx >> 5) & 15;
  int row = idx >> 9;           // 0..4095
  int t = row & 2047;
  size_t base = (size_t)row * 3072 + h * 192 + 128;
  float inv = expf(-(float)j * 0.28782313662425574f);
  float ang = (float)t * inv;
  float c, s;
  sincosf(ang, &s, &c);
  float x1 = (float)buf[base + j];
  float x2 = (float)buf[base + j + 32];
  buf[base + j]      = (bf16_t)(x1 * c - x2 * s);
  buf[base + j + 32] = (bf16_t)(x1 * s + x2 * c);
}

// ---------------------------------------------------------------- GEMM: C = A(M,lda)[:, :K] * Bt(N,K)^T
// 256(M)x128(N) tile, BK=64, 512 thr / 8 waves, per-wave 64x64.
// Phase-split schedule (m201-style): 4 phases/K-tile, each {ds_read subset |
// 2 gload_lds of tile t+2 | s_barrier | setprio1 | 8 MFMA | setprio0 | s_barrier}.
// TRIPLE-buffered LDS (144KB) so end-of-tile wait is vmcnt(6) (tile t+2 stays in
// flight); full drain only on the last two tiles.
template <int MODE>
__global__ __launch_bounds__(512, 2) void gemm_bt2(const bf16_t* __restrict__ A, int lda,
                                                   const bf16_t* __restrict__ Bt,
                                                   void* __restrict__ C0, void* __restrict__ C1,
                                                   void* __restrict__ C2, int K, int ldc) {
  __shared__ __align__(16) bf16_t sA0[256 * 64];
  __shared__ __align__(16) bf16_t sA1[256 * 64];
  __shared__ __align__(16) bf16_t sA2[256 * 64];
  __shared__ __align__(16) bf16_t sB0[128 * 64];
  __shared__ __align__(16) bf16_t sB1[128 * 64];
  __shared__ __align__(16) bf16_t sB2[128 * 64];
  const int tid = threadIdx.x;
  const int l = tid & 63, w = tid >> 6;
  const int l15 = l & 15, l4 = (l >> 4) & 3;
  const int wr = w >> 1, wc = w & 1;
  const int m0 = blockIdx.y * 256, n0 = blockIdx.x * 128;
  const int nt = K >> 6;

  f32x4 acc[4][4] = {};

#define SG_A(SA, KT, R)                                                             \
  { int i = (R) * 512 + tid; int row = i >> 3, cl = i & 7; int cg = cl ^ (row & 7); \
    gload_lds16(A + (size_t)(m0 + row) * lda + (KT) * 64 + cg * 8,                  \
                (char*)(SA) + (size_t)((R) * 512 + w * 64) * 16); }
#define SG_B(SB, KT, R)                                                             \
  { int i = (R) * 512 + tid; int row = i >> 3, cl = i & 7; int cg = cl ^ (row & 7); \
    gload_lds16(Bt + (size_t)(n0 + row) * K + (KT) * 64 + cg * 8,                   \
                (char*)(SB) + (size_t)((R) * 512 + w * 64) * 16); }
#define SG_ALL(SA, SB, KT) { SG_A(SA, KT, 0) SG_A(SA, KT, 1) SG_A(SA, KT, 2) \
                             SG_A(SA, KT, 3) SG_B(SB, KT, 0) SG_B(SB, KT, 1) }

  bf16_t *a0 = sA0, *a1 = sA1, *a2 = sA2;
  bf16_t *b0 = sB0, *b1 = sB1, *b2 = sB2;

  SG_ALL(a0, b0, 0)
  if (nt > 1) SG_ALL(a1, b1, 1)
  asm volatile("s_waitcnt vmcnt(6)\n\ts_barrier" ::: "memory");  // tile 0 landed

  for (int t = 0; t < nt; ++t) {
    const bool st = (t + 2 < nt);
    bf16x8 af[4], bfr[4];

    // ---- phase 0 (ks=0): af0-3, bfr0-1; stage A r0,r1 of t+2
#pragma unroll
    for (int mf = 0; mf < 4; mf++) {
      int row = wr * 64 + mf * 16 + l15;
      int cl = l4 ^ (row & 7);
      af[mf] = *(const bf16x8*)(a0 + row * 64 + cl * 8);
    }
#pragma unroll
    for (int nf = 0; nf < 2; nf++) {
      int row = wc * 64 + nf * 16 + l15;
      int cl = l4 ^ (row & 7);
      bfr[nf] = *(const bf16x8*)(b0 + row * 64 + cl * 8);
    }
    if (st) { SG_A(a2, t + 2, 0) SG_A(a2, t + 2, 1) }
    asm volatile("s_barrier" ::: "memory");
    __builtin_amdgcn_s_setprio(1);
#pragma unroll
    for (int mf = 0; mf < 4; mf++)
#pragma unroll
      for (int nf = 0; nf < 2; nf++)
        acc[mf][nf] = MFMA16(af[mf], bfr[nf], acc[mf][nf]);
    __builtin_amdgcn_s_setprio(0);
    asm volatile("s_barrier" ::: "memory");

    // ---- phase 1 (ks=0): bfr2-3; stage A r2,r3
#pragma unroll
    for (int nf = 2; nf < 4; nf++) {
      int row = wc * 64 + nf * 16 + l15;
      int cl = l4 ^ (row & 7);
      bfr[nf] = *(const bf16x8*)(b0 + row * 64 + cl * 8);
    }
    if (st) { SG_A(a2, t + 2, 2) SG_A(a2, t + 2, 3) }
    asm volatile("s_barrier" ::: "memory");
    __builtin_amdgcn_s_setprio(1);
#pragma unroll
    for (int mf = 0; mf < 4; mf++)
#pragma unroll
      for (int nf = 2; nf < 4; nf++)
        acc[mf][nf] = MFMA16(af[mf], bfr[nf], acc[mf][nf]);
    __builtin_amdgcn_s_setprio(0);
    asm volatile("s_barrier" ::: "memory");

    // ---- phase 2 (ks=1): af0-3, bfr0-1; stage B r0,r1
#pragma unroll
    for (int mf = 0; mf < 4; mf++) {
      int row = wr * 64 + mf * 16 + l15;
      int cl = (4 + l4) ^ (row & 7);
      af[mf] = *(const bf16x8*)(a0 + row * 64 + cl * 8);
    }
#pragma unroll
    for (int nf = 0; nf < 2; nf++) {
      int row = wc * 64 + nf * 16 + l15;
      int cl = (4 + l4) ^ (row & 7);
      bfr[nf] = *(const bf16x8*)(b0 + row * 64 + cl * 8);
    }
    if (st) { SG_B(b2, t + 2, 0) SG_B(b2, t + 2, 1) }
    asm volatile("s_barrier" ::: "memory");
    __builtin_amdgcn_s_setprio(1);
#pragma unroll
    for (int mf = 0; mf < 4; mf++)
#pragma unroll
      for (int nf = 0; nf < 2; nf++)
        acc[mf][nf] = MFMA16(af[mf], bfr[nf], acc[mf][nf]);
    __builtin_amdgcn_s_setprio(0);
    asm volatile("s_barrier" ::: "memory");

    // ---- phase 3 (ks=1): bfr2-3; end-of-tile counted wait
#pragma unroll
    for (int nf = 2; nf < 4; nf++) {
      int row = wc * 64 + nf * 16 + l15;
      int cl = (4 + l4) ^ (row & 7);
      bfr[nf] = *(const bf16x8*)(b0 + row * 64 + cl * 8);
    }
    asm volatile("s_barrier" ::: "memory");
    __builtin_amdgcn_s_setprio(1);
#pragma unroll
    for (int mf = 0; mf < 4; mf++)
#pragma unroll
      for (int nf = 2; nf < 4; nf++)
        acc[mf][nf] = MFMA16(af[mf], bfr[nf], acc[mf][nf]);
    __builtin_amdgcn_s_setprio(0);
    if (st) asm volatile("s_waitcnt vmcnt(6)" ::: "memory");   // t+1 landed, t+2 in flight
    else    asm volatile("s_waitcnt vmcnt(0)" ::: "memory");   // tail drain
    asm volatile("s_barrier" ::: "memory");

    bf16_t* ta = a0; a0 = a1; a1 = a2; a2 = ta;
    bf16_t* tb = b0; b0 = b1; b1 = b2; b2 = tb;
  }
#undef SG_A
#undef SG_B
#undef SG_ALL

#pragma unroll
  for (int mf = 0; mf < 4; mf++)
#pragma unroll
    for (int nf = 0; nf < 4; nf++) {
      const int mbase = m0 + wr * 64 + mf * 16 + l4 * 4;
      const int n = n0 + wc * 64 + nf * 16 + l15;
      if constexpr (MODE == 1) {
#pragma unroll
        for (int r = 0; r < 4; r++)
          ((float*)C0)[(size_t)(mbase + r) * ldc + n] = acc[mf][nf][r];
      } else if constexpr (MODE == 2) {
#pragma unroll
        for (int r = 0; r < 4; r++)
          ((bf16_t*)C0)[(size_t)(mbase + r) * 3072 + (n >> 7) * 192 + (n & 127)] =
              (bf16_t)acc[mf][nf][r];
      } else if constexpr (MODE == 4) {
        if (n < 1280) {
#pragma unroll
          for (int r = 0; r < 4; r++)
            ((bf16_t*)C0)[(size_t)(mbase + r) * 1280 + n] = (bf16_t)acc[mf][nf][r];
        } else if (n < 2304) {
          int nn = n - 1280;
#pragma unroll
          for (int r = 0; r < 4; r++)
            ((bf16_t*)C1)[(size_t)(mbase + r) * 3072 + (nn >> 6) * 192 + 128 + (nn & 63)] =
                (bf16_t)acc[mf][nf][r];
        } else {
          int nn = n - 2304;
#pragma unroll
          for (int r = 0; r < 4; r++)
            ((bf16_t*)C2)[(size_t)(mbase + r) * 3072 + (nn >> 6) * 192 + 128 + (nn & 63)] =
                (bf16_t)acc[mf][nf][r];
        }
      } else {  // MODE 5
        if (n < 2048) {
#pragma unroll
          for (int r = 0; r < 4; r++)
            ((bf16_t*)C0)[(size_t)(mbase + r) * 3072 + (n >> 7) * 192 + (n & 127)] =
                (bf16_t)acc[mf][nf][r];
        } else {
          // v_up -> vt (b, h, d, t) directly; 4 r-values are 4 consecutive t
          int nn = n - 2048;            // 0..3071
          int hh = nn / 192, dd = nn - hh * 192;
          int bb = mbase >> 11, tt = mbase & 2047;
          bf16_t pk4[4] = {(bf16_t)acc[mf][nf][0], (bf16_t)acc[mf][nf][1],
                           (bf16_t)acc[mf][nf][2], (bf16_t)acc[mf][nf][3]};
          *(uint2*)((bf16_t*)C1 + ((size_t)(bb * 16 + hh) * 192 + dd) * 2048 + tt) =
              *(uint2*)pk4;
        }
      }
    }
}

// ---------------------------------------------------------------- flash attention (causal)
// 8 waves / 512 threads, pairs (c,31-c) of 128-row chunks; statically distinct
// K/V double buffers, 2x-unrolled loop, gload_lds prefetch one tile ahead.
// setprio(1) around QK and PV MFMA clusters (T5).
__global__ __launch_bounds__(512, 2) void attn_kernel(const bf16_t* __restrict__ q,
                                                      const bf16_t* __restrict__ kbuf,
                                                      const bf16_t* __restrict__ vt,
                                                      bf16_t* __restrict__ ao) {
  __shared__ __align__(16) bf16_t sK0[64][192];  // perm-24 swizzle
  __shared__ __align__(16) bf16_t sK1[64][192];
  __shared__ __align__(16) bf16_t sV0[192][64];  // xor-8 chunk swizzle
  __shared__ __align__(16) bf16_t sV1[192][64];

  const int tid = threadIdx.x, l = tid & 63, w = tid >> 6;
  const int l15 = l & 15, l4 = (l >> 4) & 3;
  const int bh = blockIdx.x & 31;            // same-bh blocks share an XCD (i%8 preserved)
  const int c = blockIdx.x >> 5;             // pair index 0..7
  const int b = bh >> 4, h = bh & 15;
  const int ca = c, cb = 15 - c;             // 128-row chunks
  const int ra = ca * 128 + w * 16;
  const int rb = cb * 128 + w * 16;
  const int tga = 2 * ca + (w >> 2);         // diag k-tile for this wave's chunk-a rows
  const int tgb = 2 * cb + (w >> 2);

  const bf16_t* qp = q + (size_t)b * 2048 * 3072 + h * 192;
  const bf16_t* kp = kbuf + (size_t)b * 2048 * 3072 + h * 192;
  const bf16_t* vp = vt + (size_t)bh * 192 * 2048;

  bf16x8 qf[2][6];
#pragma unroll
  for (int kd = 0; kd < 6; kd++) {
    qf[0][kd] = *(const bf16x8*)(qp + (size_t)(ra + l15) * 3072 + kd * 32 + l4 * 8);
    qf[1][kd] = *(const bf16x8*)(qp + (size_t)(rb + l15) * 3072 + kd * 32 + l4 * 8);
  }

  f32x4 o[2][12] = {};
  float mrow[2] = {-__builtin_inff(), -__builtin_inff()};
  float lrow[2] = {0.0f, 0.0f};

  const float scale = 0.07216878364870322f;  // 1/sqrt(192)
  const float THR = 7.0f;                    // defer-max threshold
  const int nkt = 2 * cb + 2;                // always even
  const int src0 = l15 + ((l4 & 1) << 5);
  const int src1 = src0 + 16;
  const bool hibank = (l4 & 2) != 0;

#define STAGE(SK, SV, KT)                                                           \
  {                                                                                 \
    const int k0s = (KT) * 64;                                                      \
    _Pragma("unroll")                                                               \
    for (int r = 0; r < 3; r++) {                                                   \
      int i = r * 512 + tid;                                                        \
      int row = i / 24, cc = i % 24;                                                \
      int g = cc - (row & 7) * 3;                                                   \
      if (g < 0) g += 24;                                                           \
      gload_lds16(kp + (size_t)(k0s + row) * 3072 + g * 8,                          \
                  (char*)&SK[0][0] + (size_t)(r * 512 + w * 64) * 16);              \
    }                                                                               \
    _Pragma("unroll")                                                               \
    for (int r = 0; r < 3; r++) {                                                   \
      int i = r * 512 + tid;                                                        \
      int d = i >> 3, cc = i & 7;                                                   \
      gload_lds16(vp + (size_t)d * 2048 + k0s + (cc ^ (d & 7)) * 8,                 \
                  (char*)&SV[0][0] + (size_t)(r * 512 + w * 64) * 16);              \
    }                                                                               \
  }

#define SOFTMAX_CHUNK(c, rbase, tg)                                                    \
    {                                                                                  \
      const bool diag = (kt == (tg));                                                  \
      _Pragma("unroll")                                                                \
      for (int nf = 0; nf < 4; nf++)                                                   \
        _Pragma("unroll")                                                              \
        for (int r = 0; r < 4; r++) {                                                  \
          float sv = s[c][nf][r] * scale;                                              \
          if (diag) {                                                                  \
            int ktok = k0 + nf * 16 + l4 * 4 + r;                                      \
            if (ktok > (rbase) + l15) sv = -__builtin_inff();                          \
          }                                                                            \
          s[c][nf][r] = sv;                                                            \
        }                                                                              \
      float m_in = s[c][0][0];                                                         \
      _Pragma("unroll")                                                                \
      for (int nf = 0; nf < 4; nf++)                                                   \
        _Pragma("unroll")                                                              \
        for (int r = 0; r < 4; r++)                                                    \
          if (nf | r) m_in = fmaxf(m_in, s[c][nf][r]);                                 \
      m_in = fmaxf(m_in, __shfl_xor(m_in, 16));                                        \
      m_in = fmaxf(m_in, __shfl_xor(m_in, 32));                                        \
      if (!__all(m_in - mrow[c] <= THR)) {                                             \
        float mn = fmaxf(mrow[c], m_in);                                               \
        float alpha = __expf(mrow[c] - mn);                                            \
        mrow[c] = mn;                                                                  \
        lrow[c] *= alpha;                                                              \
        f32x4 av;                                                                      \
        _Pragma("unroll")                                                              \
        for (int r = 0; r < 4; r++) av[r] = __shfl(alpha, l4 * 4 + r);                 \
        _Pragma("unroll")                                                              \
        for (int nf2 = 0; nf2 < 12; nf2++) o[c][nf2] *= av;                            \
      }                                                                                \
      float rs = 0.0f;                                                                 \
      _Pragma("unroll")                                                                \
      for (int nf = 0; nf < 4; nf++)                                                   \
        _Pragma("unroll")                                                              \
        for (int r = 0; r < 4; r++) {                                                  \
          float pv = __expf(s[c][nf][r] - mrow[c]);                                    \
          s[c][nf][r] = pv;                                                            \
          rs += pv;                                                                    \
        }                                                                              \
      rs += __shfl_xor(rs, 16);                                                        \
      rs += __shfl_xor(rs, 32);                                                        \
      lrow[c] += rs;                                                                   \
      uint32_t wq[8];                                                                  \
      _Pragma("unroll")                                                                \
      for (int nf = 0; nf < 4; nf++) {                                                 \
        wq[nf * 2 + 0] = pkbf(s[c][nf][0], s[c][nf][1]);                               \
        wq[nf * 2 + 1] = pkbf(s[c][nf][2], s[c][nf][3]);                               \
      }                                                                                \
      _Pragma("unroll")                                                                \
      for (int ks = 0; ks < 2; ks++) {                                                 \
        uint32_t A0 = __shfl(wq[(2 * ks) * 2 + 0], src0);                              \
        uint32_t A1 = __shfl(wq[(2 * ks) * 2 + 1], src0);                              \
        uint32_t B0 = __shfl(wq[(2 * ks + 1) * 2 + 0], src0);                          \
        uint32_t B1 = __shfl(wq[(2 * ks + 1) * 2 + 1], src0);                          \
        uint32_t C0w = __shfl(wq[(2 * ks) * 2 + 0], src1);                             \
        uint32_t C1w = __shfl(wq[(2 * ks) * 2 + 1], src1);                             \
        uint32_t D0 = __shfl(wq[(2 * ks + 1) * 2 + 0], src1);                          \
        uint32_t D1 = __shfl(wq[(2 * ks + 1) * 2 + 1], src1);                          \
        union { uint32_t u[4]; bf16x8 v; } fr;                                         \
        fr.u[0] = hibank ? B0 : A0;                                                    \
        fr.u[1] = hibank ? B1 : A1;                                                    \
        fr.u[2] = hibank ? D0 : C0w;                                                   \
        fr.u[3] = hibank ? D1 : C1w;                                                   \
        pa[c][ks] = fr.v;                                                              \
      }                                                                                \
    }

#define TILE_BODY(SK, SV, KT)                                                          \
  {                                                                                    \
    const int kt = (KT);                                                               \
    const int k0 = kt * 64;                                                            \
    const bool act_a = (kt <= tga);                                                    \
    const bool act_b = (kt <= tgb);                                                    \
    f32x4 s[2][4] = {};                                                                \
    __builtin_amdgcn_s_setprio(1);                                                     \
    _Pragma("unroll")                                                                  \
    for (int kd = 0; kd < 6; kd++) {                                                   \
      bf16x8 bk[4];                                                                    \
      _Pragma("unroll")                                                                \
      for (int nf = 0; nf < 4; nf++) {                                                 \
        int row = nf * 16 + l15;                                                       \
        int cl = kd * 4 + l4 + (row & 7) * 3;                                          \
        if (cl >= 24) cl -= 24;                                                        \
        bk[nf] = *(const bf16x8*)(&SK[row][cl * 8]);                                   \
      }                                                                                \
      if (act_b) {                                                                     \
        _Pragma("unroll")                                                              \
        for (int nf = 0; nf < 4; nf++)                                                 \
          s[1][nf] = MFMA16(bk[nf], qf[1][kd], s[1][nf]);                              \
      }                                                                                \
      if (act_a) {                                                                     \
        _Pragma("unroll")                                                              \
        for (int nf = 0; nf < 4; nf++)                                                 \
          s[0][nf] = MFMA16(bk[nf], qf[0][kd], s[0][nf]);                              \
      }                                                                                \
    }                                                                                  \
    __builtin_amdgcn_s_setprio(0);                                                     \
    bf16x8 pa[2][2] = {};                                                              \
    if (act_b) SOFTMAX_CHUNK(1, rb, tgb)                                               \
    if (act_a) SOFTMAX_CHUNK(0, ra, tga)                                               \
    __builtin_amdgcn_s_setprio(1);                                                     \
    _Pragma("unroll")                                                                  \
    for (int ks = 0; ks < 2; ks++) {                                                   \
      _Pragma("unroll")                                                                \
      for (int nf2 = 0; nf2 < 12; nf2++) {                                             \
        int d = nf2 * 16 + l15;                                                        \
        int cl = (ks * 4 + l4) ^ (d & 7);                                              \
        bf16x8 vb = *(const bf16x8*)(&SV[d][cl * 8]);                                  \
        if (act_b) o[1][nf2] = MFMA16(pa[1][ks], vb, o[1][nf2]);                       \
        if (act_a) o[0][nf2] = MFMA16(pa[0][ks], vb, o[0][nf2]);                       \
      }                                                                                \
    }                                                                                  \
    __builtin_amdgcn_s_setprio(0);                                                     \
  }

  STAGE(sK0, sV0, 0)
  __syncthreads();  // tile 0 ready

  for (int kt0 = 0; kt0 < nkt; kt0 += 2) {
    STAGE(sK1, sV1, kt0 + 1)
    TILE_BODY(sK0, sV0, kt0)
    __syncthreads();
    if (kt0 + 2 < nkt) STAGE(sK0, sV0, kt0 + 2)
    TILE_BODY(sK1, sV1, kt0 + 1)
    __syncthreads();
  }
#undef STAGE
#undef SOFTMAX_CHUNK
#undef TILE_BODY

  // epilogue: O/l -> ao (b*T+q, h*192+d), both chunks; l lives at lane l15=q
#pragma unroll
  for (int mf = 0; mf < 2; mf++) {
    const int rbase = (mf == 0) ? ra : rb;
#pragma unroll
    for (int r = 0; r < 4; r++) {
      float lv = __shfl(lrow[mf], l4 * 4 + r);
      float inv = 1.0f / lv;
      int qrow = rbase + l4 * 4 + r;
#pragma unroll
      for (int nf2 = 0; nf2 < 12; nf2++) {
        int d = nf2 * 16 + l15;
        ao[(size_t)(b * 2048 + qrow) * 3072 + h * 192 + d] = (bf16_t)(o[mf][nf2][r] * inv);
      }
    }
  }
}

// ----------------------------------------------------------------
extern "C" void kernel_launch(void* const* d_in, const int* in_sizes, int n_in,
                              void* d_out, int out_size, void* d_ws, size_t ws_size,
                              hipStream_t stream) {
  const float* x       = (const float*)d_in[0];
  const float* wq_down = (const float*)d_in[1];
  const float* wq_up   = (const float*)d_in[2];
  const float* wq_rope = (const float*)d_in[3];
  const float* wkv_down= (const float*)d_in[4];
  const float* wk_up   = (const float*)d_in[5];
  const float* wv_up   = (const float*)d_in[6];
  const float* wk_rope = (const float*)d_in[7];
  const float* wo      = (const float*)d_in[8];
  float* out = (float*)d_out;

  char* p = (char*)d_ws;
  auto take = [&](size_t elems) { bf16_t* r = (bf16_t*)p; p += elems * 2; return r; };
  bf16_t* xb    = take(4096ull * 2048);
  bf16_t* fw1   = take(3328ull * 2048);  // [wq_down(768) | wkv_down(512) | wq_rope(1024) | wk_rope(1024)]^T
  bf16_t* wqu_t = take(2048ull * 768);
  bf16_t* fw2   = take(5120ull * 512);   // [wk_up(2048) | wv_up(3072)]^T
  bf16_t* wo_t  = take(2048ull * 3072);
  bf16_t* qkvd  = take(4096ull * 1280);  // [q_down(768) | latent(512)]
  bf16_t* qbuf  = take(4096ull * 3072);
  bf16_t* kbuf  = take(4096ull * 3072);
  bf16_t* ao    = take(4096ull * 3072);
  bf16_t* vt    = take(4096ull * 3072);

  dim3 tb(32, 8);
  cvt_f32_to_bf16<<<8192, 256, 0, stream>>>(x, xb);
  transpose_all<<<16896, tb, 0, stream>>>(
      wq_down, wkv_down, wq_rope, wk_rope, wq_up, wk_up, wv_up, wo,
      fw1, fw1 + 768ull * 2048, fw1 + 1280ull * 2048, fw1 + 2304ull * 2048,
      wqu_t, fw2, fw2 + 2048ull * 512, wo_t);

  gemm_bt2<4><<<dim3(26, 16), 512, 0, stream>>>(xb, 2048, fw1, qkvd, qbuf, kbuf, 2048, 0);
  gemm_bt2<2><<<dim3(16, 16), 512, 0, stream>>>(qkvd, 1280, wqu_t, qbuf, nullptr, nullptr, 768, 0);
  gemm_bt2<5><<<dim3(40, 16), 512, 0, stream>>>(qkvd + 768, 1280, fw2, kbuf, vt, nullptr, 512, 0);

  rope_both<<<16384, 256, 0, stream>>>(qbuf, kbuf);

  attn_kernel<<<256, 512, 0, stream>>>(qbuf, kbuf, vt, ao);

  gemm_bt2<1><<<dim3(16, 16), 512, 0, stream>>>(ao, 3072, wo_t, out, nullptr, nullptr, 3072, 2048);
}

// Round 11
// 326.392 us; speedup vs baseline: 1.2957x; 1.0458x over previous
//
#include <hip/hip_runtime.h>
#include <hip/hip_bf16.h>
#include <cstdint>
#include <cstddef>

typedef __bf16 bf16_t;
typedef __bf16 bf16x8 __attribute__((ext_vector_type(8)));
typedef float f32x4 __attribute__((ext_vector_type(4)));

#define MFMA16(a, b, c) __builtin_amdgcn_mfma_f32_16x16x32_bf16((a), (b), (c), 0, 0, 0)

__device__ __forceinline__ void gload_lds16(const void* g, void* l) {
  __builtin_amdgcn_global_load_lds((__attribute__((address_space(1))) void*)(g),
                                   (__attribute__((address_space(3))) void*)(l),
                                   16, 0, 0);
}

__device__ __forceinline__ uint32_t pkbf(float lo, float hi) {
  union { bf16_t h[2]; uint32_t u; } u2;
  u2.h[0] = (bf16_t)lo; u2.h[1] = (bf16_t)hi;
  return u2.u;
}

// ---------------------------------------------------------------- cvt x fp32->bf16
__global__ __launch_bounds__(256) void cvt_f32_to_bf16(const float* __restrict__ in,
                                                       bf16_t* __restrict__ out) {
  size_t i = ((size_t)blockIdx.x * 256 + threadIdx.x) * 4;
  float4 v = *(const float4*)(in + i);
  bf16_t o[4] = {(bf16_t)v.x, (bf16_t)v.y, (bf16_t)v.z, (bf16_t)v.w};
  *(uint2*)(out + i) = *(uint2*)o;
}

// ---------------------------------------------------------------- all 8 weight transposes, one dispatch
__global__ __launch_bounds__(256) void transpose_all(
    const float* __restrict__ s0, const float* __restrict__ s1,
    const float* __restrict__ s2, const float* __restrict__ s3,
    const float* __restrict__ s4, const float* __restrict__ s5,
    const float* __restrict__ s6, const float* __restrict__ s7,
    bf16_t* __restrict__ t0, bf16_t* __restrict__ t1, bf16_t* __restrict__ t2,
    bf16_t* __restrict__ t3, bf16_t* __restrict__ t4, bf16_t* __restrict__ t5,
    bf16_t* __restrict__ t6, bf16_t* __restrict__ t7) {
  __shared__ bf16_t tile[32][33];
  const int lid = blockIdx.x;
  const float* src; bf16_t* dst; int R, C, bx, by;
  if (lid < 1536)       { src=s0; dst=t0; R=2048; C=768;  int lo=lid;        bx=lo%24; by=lo/24; }
  else if (lid < 2560)  { src=s1; dst=t1; R=2048; C=512;  int lo=lid-1536;   bx=lo%16; by=lo/16; }
  else if (lid < 4608)  { src=s2; dst=t2; R=2048; C=1024; int lo=lid-2560;   bx=lo%32; by=lo/32; }
  else if (lid < 6656)  { src=s3; dst=t3; R=2048; C=1024; int lo=lid-4608;   bx=lo%32; by=lo/32; }
  else if (lid < 8192)  { src=s4; dst=t4; R=768;  C=2048; int lo=lid-6656;   bx=lo%64; by=lo/64; }
  else if (lid < 9216)  { src=s5; dst=t5; R=512;  C=2048; int lo=lid-8192;   bx=lo%64; by=lo/64; }
  else if (lid < 10752) { src=s6; dst=t6; R=512;  C=3072; int lo=lid-9216;   bx=lo%96; by=lo/96; }
  else                  { src=s7; dst=t7; R=3072; C=2048; int lo=lid-10752;  bx=lo%64; by=lo/64; }
  const int c0 = bx * 32, r0 = by * 32;
  const int tx = threadIdx.x, ty = threadIdx.y;
#pragma unroll
  for (int s = 0; s < 4; s++) {
    int r = ty + s * 8;
    tile[r][tx] = (bf16_t)src[(size_t)(r0 + r) * C + c0 + tx];
  }
  __syncthreads();
#pragma unroll
  for (int s = 0; s < 4; s++) {
    int r = ty + s * 8;
    dst[(size_t)(c0 + r) * R + r0 + tx] = tile[tx][r];
  }
}

// ---------------------------------------------------------------- rope in-place on both packed (4096,3072) buffers
__global__ __launch_bounds__(256) void rope_both(bf16_t* __restrict__ qb,
                                                 bf16_t* __restrict__ kb) {
  const int gid = blockIdx.x;
  bf16_t* buf = (gid < 8192) ? qb : kb;
  int idx = (gid & 8191) * 256 + threadIdx.x;
  int j = idx & 31;
  int h = (idx >> 5) & 15;
  int row = idx >> 9;           // 0..4095
  int t = row & 2047;
  size_t base = (size_t)row * 3072 + h * 192 + 128;
  float inv = expf(-(float)j * 0.28782313662425574f);
  float ang = (float)t * inv;
  float c, s;
  sincosf(ang, &s, &c);
  float x1 = (float)buf[base + j];
  float x2 = (float)buf[base + j + 32];
  buf[base + j]      = (bf16_t)(x1 * c - x2 * s);
  buf[base + j + 32] = (bf16_t)(x1 * s + x2 * c);
}

// ---------------------------------------------------------------- GEMM: C = A(M,lda)[:, :K] * Bt(N,K)^T
// 128x128 tile, BK=64, 512 thr / 8 waves (wr=w>>1 over M: 32 rows, wc=w&1 over N: 64 cols),
// per-wave 32x64 (2x4 frags). Double-buffered (64KB LDS -> 2 blocks/CU), staging one
// K-step ahead with counted vmcnt(4) + raw s_barrier; unroll-2 static buffers. K/64 even.
template <int MODE>
__global__ __launch_bounds__(512, 4) void gemm128(const bf16_t* __restrict__ A, int lda,
                                                  const bf16_t* __restrict__ Bt,
                                                  void* __restrict__ C0, void* __restrict__ C1,
                                                  void* __restrict__ C2, int K, int ldc) {
  __shared__ __align__(16) bf16_t sA0[128 * 64];
  __shared__ __align__(16) bf16_t sB0[128 * 64];
  __shared__ __align__(16) bf16_t sA1[128 * 64];
  __shared__ __align__(16) bf16_t sB1[128 * 64];
  const int tid = threadIdx.x;
  const int l = tid & 63, w = tid >> 6;
  const int l15 = l & 15, l4 = (l >> 4) & 3;
  const int wr = w >> 1, wc = w & 1;
  const int m0 = blockIdx.y * 128, n0 = blockIdx.x * 128;
  const int nt = K >> 6;

  f32x4 acc[2][4] = {};

#define STAGEG(SA, SB, KT)                                                          \
  {                                                                                 \
    const int kts = (KT) * 64;                                                      \
    _Pragma("unroll")                                                               \
    for (int r = 0; r < 2; r++) {                                                   \
      int i = r * 512 + tid;                                                        \
      int row = i >> 3, cl = i & 7;                                                 \
      int cg = cl ^ (row & 7);                                                      \
      gload_lds16(A + (size_t)(m0 + row) * lda + kts + cg * 8,                      \
                  (char*)(SA) + (size_t)(r * 512 + w * 64) * 16);                   \
    }                                                                               \
    _Pragma("unroll")                                                               \
    for (int r = 0; r < 2; r++) {                                                   \
      int i = r * 512 + tid;                                                        \
      int row = i >> 3, cl = i & 7;                                                 \
      int cg = cl ^ (row & 7);                                                      \
      gload_lds16(Bt + (size_t)(n0 + row) * K + kts + cg * 8,                       \
                  (char*)(SB) + (size_t)(r * 512 + w * 64) * 16);                   \
    }                                                                               \
  }

#define GCOMPUTE(SA, SB)                                                            \
  {                                                                                 \
    _Pragma("unroll")                                                               \
    for (int ks = 0; ks < 2; ks++) {                                                \
      bf16x8 af[2], bfr[4];                                                         \
      _Pragma("unroll")                                                             \
      for (int mf = 0; mf < 2; mf++) {                                              \
        int row = wr * 32 + mf * 16 + l15;                                          \
        int cl = (ks * 4 + l4) ^ (row & 7);                                         \
        af[mf] = *(const bf16x8*)((SA) + row * 64 + cl * 8);                        \
      }                                                                             \
      _Pragma("unroll")                                                             \
      for (int nf = 0; nf < 4; nf++) {                                              \
        int row = wc * 64 + nf * 16 + l15;                                          \
        int cl = (ks * 4 + l4) ^ (row & 7);                                         \
        bfr[nf] = *(const bf16x8*)((SB) + row * 64 + cl * 8);                       \
      }                                                                             \
      __builtin_amdgcn_s_setprio(1);                                                \
      _Pragma("unroll")                                                             \
      for (int mf = 0; mf < 2; mf++)                                                \
        _Pragma("unroll")                                                           \
        for (int nf = 0; nf < 4; nf++)                                              \
          acc[mf][nf] = MFMA16(af[mf], bfr[nf], acc[mf][nf]);                       \
      __builtin_amdgcn_s_setprio(0);                                                \
    }                                                                               \
  }

  STAGEG(sA0, sB0, 0)
  for (int t = 0; t < nt; t += 2) {
    STAGEG(sA1, sB1, t + 1)                      // prefetch odd tile
    asm volatile("s_waitcnt vmcnt(4)\n\ts_barrier" ::: "memory");  // tile t landed
    GCOMPUTE(sA0, sB0)
    asm volatile("s_barrier" ::: "memory");
    if (t + 2 < nt) {
      STAGEG(sA0, sB0, t + 2)
      asm volatile("s_waitcnt vmcnt(4)\n\ts_barrier" ::: "memory");  // tile t+1 landed
    } else {
      asm volatile("s_waitcnt vmcnt(0)\n\ts_barrier" ::: "memory");  // tail drain
    }
    GCOMPUTE(sA1, sB1)
    asm volatile("s_barrier" ::: "memory");
  }
#undef STAGEG
#undef GCOMPUTE

#pragma unroll
  for (int mf = 0; mf < 2; mf++)
#pragma unroll
    for (int nf = 0; nf < 4; nf++) {
      const int mbase = m0 + wr * 32 + mf * 16 + l4 * 4;
      const int n = n0 + wc * 64 + nf * 16 + l15;
      if constexpr (MODE == 1) {
#pragma unroll
        for (int r = 0; r < 4; r++)
          ((float*)C0)[(size_t)(mbase + r) * ldc + n] = acc[mf][nf][r];
      } else if constexpr (MODE == 2) {
#pragma unroll
        for (int r = 0; r < 4; r++)
          ((bf16_t*)C0)[(size_t)(mbase + r) * 3072 + (n >> 7) * 192 + (n & 127)] =
              (bf16_t)acc[mf][nf][r];
      } else if constexpr (MODE == 4) {
        if (n < 1280) {
#pragma unroll
          for (int r = 0; r < 4; r++)
            ((bf16_t*)C0)[(size_t)(mbase + r) * 1280 + n] = (bf16_t)acc[mf][nf][r];
        } else if (n < 2304) {
          int nn = n - 1280;
#pragma unroll
          for (int r = 0; r < 4; r++)
            ((bf16_t*)C1)[(size_t)(mbase + r) * 3072 + (nn >> 6) * 192 + 128 + (nn & 63)] =
                (bf16_t)acc[mf][nf][r];
        } else {
          int nn = n - 2304;
#pragma unroll
          for (int r = 0; r < 4; r++)
            ((bf16_t*)C2)[(size_t)(mbase + r) * 3072 + (nn >> 6) * 192 + 128 + (nn & 63)] =
                (bf16_t)acc[mf][nf][r];
        }
      } else {  // MODE 5
        if (n < 2048) {
#pragma unroll
          for (int r = 0; r < 4; r++)
            ((bf16_t*)C0)[(size_t)(mbase + r) * 3072 + (n >> 7) * 192 + (n & 127)] =
                (bf16_t)acc[mf][nf][r];
        } else {
          // v_up -> vt (b, h, d, t) directly; 4 r-values are 4 consecutive t
          int nn = n - 2048;            // 0..3071
          int hh = nn / 192, dd = nn - hh * 192;
          int bb = mbase >> 11, tt = mbase & 2047;
          bf16_t pk4[4] = {(bf16_t)acc[mf][nf][0], (bf16_t)acc[mf][nf][1],
                           (bf16_t)acc[mf][nf][2], (bf16_t)acc[mf][nf][3]};
          *(uint2*)((bf16_t*)C1 + ((size_t)(bb * 16 + hh) * 192 + dd) * 2048 + tt) =
              *(uint2*)pk4;
        }
      }
    }
}

// ---------------------------------------------------------------- flash attention (causal)
// 8 waves / 512 threads, pairs (c,31-c) of 128-row chunks; statically distinct
// K/V double buffers, 2x-unrolled loop, gload_lds prefetch one tile ahead.
// setprio(1) around QK and PV MFMA clusters (T5).
__global__ __launch_bounds__(512, 2) void attn_kernel(const bf16_t* __restrict__ q,
                                                      const bf16_t* __restrict__ kbuf,
                                                      const bf16_t* __restrict__ vt,
                                                      bf16_t* __restrict__ ao) {
  __shared__ __align__(16) bf16_t sK0[64][192];  // perm-24 swizzle
  __shared__ __align__(16) bf16_t sK1[64][192];
  __shared__ __align__(16) bf16_t sV0[192][64];  // xor-8 chunk swizzle
  __shared__ __align__(16) bf16_t sV1[192][64];

  const int tid = threadIdx.x, l = tid & 63, w = tid >> 6;
  const int l15 = l & 15, l4 = (l >> 4) & 3;
  const int bh = blockIdx.x & 31;            // same-bh blocks share an XCD (i%8 preserved)
  const int c = blockIdx.x >> 5;             // pair index 0..7
  const int b = bh >> 4, h = bh & 15;
  const int ca = c, cb = 15 - c;             // 128-row chunks
  const int ra = ca * 128 + w * 16;
  const int rb = cb * 128 + w * 16;
  const int tga = 2 * ca + (w >> 2);         // diag k-tile for this wave's chunk-a rows
  const int tgb = 2 * cb + (w >> 2);

  const bf16_t* qp = q + (size_t)b * 2048 * 3072 + h * 192;
  const bf16_t* kp = kbuf + (size_t)b * 2048 * 3072 + h * 192;
  const bf16_t* vp = vt + (size_t)bh * 192 * 2048;

  bf16x8 qf[2][6];
#pragma unroll
  for (int kd = 0; kd < 6; kd++) {
    qf[0][kd] = *(const bf16x8*)(qp + (size_t)(ra + l15) * 3072 + kd * 32 + l4 * 8);
    qf[1][kd] = *(const bf16x8*)(qp + (size_t)(rb + l15) * 3072 + kd * 32 + l4 * 8);
  }

  f32x4 o[2][12] = {};
  float mrow[2] = {-__builtin_inff(), -__builtin_inff()};
  float lrow[2] = {0.0f, 0.0f};

  const float scale = 0.07216878364870322f;  // 1/sqrt(192)
  const float THR = 7.0f;                    // defer-max threshold
  const int nkt = 2 * cb + 2;                // always even
  const int src0 = l15 + ((l4 & 1) << 5);
  const int src1 = src0 + 16;
  const bool hibank = (l4 & 2) != 0;

#define STAGE(SK, SV, KT)                                                           \
  {                                                                                 \
    const int k0s = (KT) * 64;                                                      \
    _Pragma("unroll")                                                               \
    for (int r = 0; r < 3; r++) {                                                   \
      int i = r * 512 + tid;                                                        \
      int row = i / 24, cc = i % 24;                                                \
      int g = cc - (row & 7) * 3;                                                   \
      if (g < 0) g += 24;                                                           \
      gload_lds16(kp + (size_t)(k0s + row) * 3072 + g * 8,                          \
                  (char*)&SK[0][0] + (size_t)(r * 512 + w * 64) * 16);              \
    }                                                                               \
    _Pragma("unroll")                                                               \
    for (int r = 0; r < 3; r++) {                                                   \
      int i = r * 512 + tid;                                                        \
      int d = i >> 3, cc = i & 7;                                                   \
      gload_lds16(vp + (size_t)d * 2048 + k0s + (cc ^ (d & 7)) * 8,                 \
                  (char*)&SV[0][0] + (size_t)(r * 512 + w * 64) * 16);              \
    }                                                                               \
  }

#define SOFTMAX_CHUNK(c, rbase, tg)                                                    \
    {                                                                                  \
      const bool diag = (kt == (tg));                                                  \
      _Pragma("unroll")                                                                \
      for (int nf = 0; nf < 4; nf++)                                                   \
        _Pragma("unroll")                                                              \
        for (int r = 0; r < 4; r++) {                                                  \
          float sv = s[c][nf][r] * scale;                                              \
          if (diag) {                                                                  \
            int ktok = k0 + nf * 16 + l4 * 4 + r;                                      \
            if (ktok > (rbase) + l15) sv = -__builtin_inff();                          \
          }                                                                            \
          s[c][nf][r] = sv;                                                            \
        }                                                                              \
      float m_in = s[c][0][0];                                                         \
      _Pragma("unroll")                                                                \
      for (int nf = 0; nf < 4; nf++)                                                   \
        _Pragma("unroll")                                                              \
        for (int r = 0; r < 4; r++)                                                    \
          if (nf | r) m_in = fmaxf(m_in, s[c][nf][r]);                                 \
      m_in = fmaxf(m_in, __shfl_xor(m_in, 16));                                        \
      m_in = fmaxf(m_in, __shfl_xor(m_in, 32));                                        \
      if (!__all(m_in - mrow[c] <= THR)) {                                             \
        float mn = fmaxf(mrow[c], m_in);                                               \
        float alpha = __expf(mrow[c] - mn);                                            \
        mrow[c] = mn;                                                                  \
        lrow[c] *= alpha;                                                              \
        f32x4 av;                                                                      \
        _Pragma("unroll")                                                              \
        for (int r = 0; r < 4; r++) av[r] = __shfl(alpha, l4 * 4 + r);                 \
        _Pragma("unroll")                                                              \
        for (int nf2 = 0; nf2 < 12; nf2++) o[c][nf2] *= av;                            \
      }                                                                                \
      float rs = 0.0f;                                                                 \
      _Pragma("unroll")                                                                \
      for (int nf = 0; nf < 4; nf++)                                                   \
        _Pragma("unroll")                                                              \
        for (int r = 0; r < 4; r++) {                                                  \
          float pv = __expf(s[c][nf][r] - mrow[c]);                                    \
          s[c][nf][r] = pv;                                                            \
          rs += pv;                                                                    \
        }                                                                              \
      rs += __shfl_xor(rs, 16);                                                        \
      rs += __shfl_xor(rs, 32);                                                        \
      lrow[c] += rs;                                                                   \
      uint32_t wq[8];                                                                  \
      _Pragma("unroll")                                                                \
      for (int nf = 0; nf < 4; nf++) {                                                 \
        wq[nf * 2 + 0] = pkbf(s[c][nf][0], s[c][nf][1]);                               \
        wq[nf * 2 + 1] = pkbf(s[c][nf][2], s[c][nf][3]);                               \
      }                                                                                \
      _Pragma("unroll")                                                                \
      for (int ks = 0; ks < 2; ks++) {                                                 \
        uint32_t A0 = __shfl(wq[(2 * ks) * 2 + 0], src0);                              \
        uint32_t A1 = __shfl(wq[(2 * ks) * 2 + 1], src0);                              \
        uint32_t B0 = __shfl(wq[(2 * ks + 1) * 2 + 0], src0);                          \
        uint32_t B1 = __shfl(wq[(2 * ks + 1) * 2 + 1], src0);                          \
        uint32_t C0w = __shfl(wq[(2 * ks) * 2 + 0], src1);                             \
        uint32_t C1w = __shfl(wq[(2 * ks) * 2 + 1], src1);                             \
        uint32_t D0 = __shfl(wq[(2 * ks + 1) * 2 + 0], src1);                          \
        uint32_t D1 = __shfl(wq[(2 * ks + 1) * 2 + 1], src1);                          \
        union { uint32_t u[4]; bf16x8 v; } fr;                                         \
        fr.u[0] = hibank ? B0 : A0;                                                    \
        fr.u[1] = hibank ? B1 : A1;                                                    \
        fr.u[2] = hibank ? D0 : C0w;                                                   \
        fr.u[3] = hibank ? D1 : C1w;                                                   \
        pa[c][ks] = fr.v;                                                              \
      }                                                                                \
    }

#define TILE_BODY(SK, SV, KT)                                                          \
  {                                                                                    \
    const int kt = (KT);                                                               \
    const int k0 = kt * 64;                                                            \
    const bool act_a = (kt <= tga);                                                    \
    const bool act_b = (kt <= tgb);                                                    \
    f32x4 s[2][4] = {};                                                                \
    __builtin_amdgcn_s_setprio(1);                                                     \
    _Pragma("unroll")                                                                  \
    for (int kd = 0; kd < 6; kd++) {                                                   \
      bf16x8 bk[4];                                                                    \
      _Pragma("unroll")                                                                \
      for (int nf = 0; nf < 4; nf++) {                                                 \
        int row = nf * 16 + l15;                                                       \
        int cl = kd * 4 + l4 + (row & 7) * 3;                                          \
        if (cl >= 24) cl -= 24;                                                        \
        bk[nf] = *(const bf16x8*)(&SK[row][cl * 8]);                                   \
      }                                                                                \
      if (act_b) {                                                                     \
        _Pragma("unroll")                                                              \
        for (int nf = 0; nf < 4; nf++)                                                 \
          s[1][nf] = MFMA16(bk[nf], qf[1][kd], s[1][nf]);                              \
      }                                                                                \
      if (act_a) {                                                                     \
        _Pragma("unroll")                                                              \
        for (int nf = 0; nf < 4; nf++)                                                 \
          s[0][nf] = MFMA16(bk[nf], qf[0][kd], s[0][nf]);                              \
      }                                                                                \
    }                                                                                  \
    __builtin_amdgcn_s_setprio(0);                                                     \
    bf16x8 pa[2][2] = {};                                                              \
    if (act_b) SOFTMAX_CHUNK(1, rb, tgb)                                               \
    if (act_a) SOFTMAX_CHUNK(0, ra, tga)                                               \
    __builtin_amdgcn_s_setprio(1);                                                     \
    _Pragma("unroll")                                                                  \
    for (int ks = 0; ks < 2; ks++) {                                                   \
      _Pragma("unroll")                                                                \
      for (int nf2 = 0; nf2 < 12; nf2++) {                                             \
        int d = nf2 * 16 + l15;                                                        \
        int cl = (ks * 4 + l4) ^ (d & 7);                                              \
        bf16x8 vb = *(const bf16x8*)(&SV[d][cl * 8]);                                  \
        if (act_b) o[1][nf2] = MFMA16(pa[1][ks], vb, o[1][nf2]);                       \
        if (act_a) o[0][nf2] = MFMA16(pa[0][ks], vb, o[0][nf2]);                       \
      }                                                                                \
    }                                                                                  \
    __builtin_amdgcn_s_setprio(0);                                                     \
  }

  STAGE(sK0, sV0, 0)
  __syncthreads();  // tile 0 ready

  for (int kt0 = 0; kt0 < nkt; kt0 += 2) {
    STAGE(sK1, sV1, kt0 + 1)
    TILE_BODY(sK0, sV0, kt0)
    __syncthreads();
    if (kt0 + 2 < nkt) STAGE(sK0, sV0, kt0 + 2)
    TILE_BODY(sK1, sV1, kt0 + 1)
    __syncthreads();
  }
#undef STAGE
#undef SOFTMAX_CHUNK
#undef TILE_BODY

  // epilogue: O/l -> ao (b*T+q, h*192+d), both chunks; l lives at lane l15=q
#pragma unroll
  for (int mf = 0; mf < 2; mf++) {
    const int rbase = (mf == 0) ? ra : rb;
#pragma unroll
    for (int r = 0; r < 4; r++) {
      float lv = __shfl(lrow[mf], l4 * 4 + r);
      float inv = 1.0f / lv;
      int qrow = rbase + l4 * 4 + r;
#pragma unroll
      for (int nf2 = 0; nf2 < 12; nf2++) {
        int d = nf2 * 16 + l15;
        ao[(size_t)(b * 2048 + qrow) * 3072 + h * 192 + d] = (bf16_t)(o[mf][nf2][r] * inv);
      }
    }
  }
}

// ----------------------------------------------------------------
extern "C" void kernel_launch(void* const* d_in, const int* in_sizes, int n_in,
                              void* d_out, int out_size, void* d_ws, size_t ws_size,
                              hipStream_t stream) {
  const float* x       = (const float*)d_in[0];
  const float* wq_down = (const float*)d_in[1];
  const float* wq_up   = (const float*)d_in[2];
  const float* wq_rope = (const float*)d_in[3];
  const float* wkv_down= (const float*)d_in[4];
  const float* wk_up   = (const float*)d_in[5];
  const float* wv_up   = (const float*)d_in[6];
  const float* wk_rope = (const float*)d_in[7];
  const float* wo      = (const float*)d_in[8];
  float* out = (float*)d_out;

  char* p = (char*)d_ws;
  auto take = [&](size_t elems) { bf16_t* r = (bf16_t*)p; p += elems * 2; return r; };
  bf16_t* xb    = take(4096ull * 2048);
  bf16_t* fw1   = take(3328ull * 2048);  // [wq_down(768) | wkv_down(512) | wq_rope(1024) | wk_rope(1024)]^T
  bf16_t* wqu_t = take(2048ull * 768);
  bf16_t* fw2   = take(5120ull * 512);   // [wk_up(2048) | wv_up(3072)]^T
  bf16_t* wo_t  = take(2048ull * 3072);
  bf16_t* qkvd  = take(4096ull * 1280);  // [q_down(768) | latent(512)]
  bf16_t* qbuf  = take(4096ull * 3072);
  bf16_t* kbuf  = take(4096ull * 3072);
  bf16_t* ao    = take(4096ull * 3072);
  bf16_t* vt    = take(4096ull * 3072);

  dim3 tb(32, 8);
  cvt_f32_to_bf16<<<8192, 256, 0, stream>>>(x, xb);
  transpose_all<<<16896, tb, 0, stream>>>(
      wq_down, wkv_down, wq_rope, wk_rope, wq_up, wk_up, wv_up, wo,
      fw1, fw1 + 768ull * 2048, fw1 + 1280ull * 2048, fw1 + 2304ull * 2048,
      wqu_t, fw2, fw2 + 2048ull * 512, wo_t);

  gemm128<4><<<dim3(26, 32), 512, 0, stream>>>(xb, 2048, fw1, qkvd, qbuf, kbuf, 2048, 0);
  gemm128<2><<<dim3(16, 32), 512, 0, stream>>>(qkvd, 1280, wqu_t, qbuf, nullptr, nullptr, 768, 0);
  gemm128<5><<<dim3(40, 32), 512, 0, stream>>>(qkvd + 768, 1280, fw2, kbuf, vt, nullptr, 512, 0);

  rope_both<<<16384, 256, 0, stream>>>(qbuf, kbuf);

  attn_kernel<<<256, 512, 0, stream>>>(qbuf, kbuf, vt, ao);

  gemm128<1><<<dim3(16, 32), 512, 0, stream>>>(ao, 3072, wo_t, out, nullptr, nullptr, 3072, 2048);
}